// Round 2
// 1006.321 us; speedup vs baseline: 1.1895x; 1.1895x over previous
//
#include <hip/hip_runtime.h>
#include <cstdint>

typedef short s16x8 __attribute__((ext_vector_type(8)));
typedef float f32x4 __attribute__((ext_vector_type(4)));
typedef unsigned short u16;

#define DEV static __device__ __forceinline__

DEV float bf2f(u16 b) {
  union { unsigned u; float f; } v; v.u = ((unsigned)b) << 16; return v.f;
}
DEV u16 f2bf(float f) {
  union { float f; unsigned u; } v; v.f = f;
  unsigned r = 0x7fffu + ((v.u >> 16) & 1u);   // RNE
  return (u16)((v.u + r) >> 16);
}

typedef __attribute__((address_space(3))) void lds_void_t;
typedef const __attribute__((address_space(1))) void glob_void_t;

DEV void async_copy16(const void* g, void* l) {
  __builtin_amdgcn_global_load_lds(
      (glob_void_t*)(uintptr_t)g,
      (lds_void_t*)(uint32_t)(uintptr_t)l,
      16, 0, 0);
}

// ---------------- fp32 -> bf16 convert (vectorized x4) ----------------
__global__ void cvt_f32_bf16(const float* __restrict__ in, u16* __restrict__ out, int n4) {
  int i = blockIdx.x * 256 + threadIdx.x;
  if (i < n4) {
    const float4 v = reinterpret_cast<const float4*>(in)[i];
    ushort4 o;
    o.x = f2bf(v.x); o.y = f2bf(v.y); o.z = f2bf(v.z); o.w = f2bf(v.w);
    reinterpret_cast<ushort4*>(out)[i] = o;
  }
}

// ---------------- NT GEMM: C[m,n] = sum_k A[m,k]*B[n,k] ----------------
// (unchanged — isolating the attn staging rewrite this round)
template <bool OUT_BF16>
__global__ __launch_bounds__(256, 2)
void gemm_nt(const u16* __restrict__ A, const u16* __restrict__ B,
             void* __restrict__ C, int M, int N, int K) {
  __shared__ u16 As[128 * 32];
  __shared__ u16 Bs[128 * 32];
  const int tid  = threadIdx.x;
  const int lane = tid & 63;
  const int wave = tid >> 6;
  const int wr = wave >> 1, wc = wave & 1;
  const int l15 = lane & 15, quad = lane >> 4;
  const int bm = blockIdx.x, bn = blockIdx.y;

  const int srow   = lane >> 2;
  const int schunk = (lane & 3) ^ ((srow >> 1) & 3);
  const int fsw    = (l15 >> 1) & 3;

  f32x4 acc[4][4];
  const f32x4 zero4 = {0.f, 0.f, 0.f, 0.f};
#pragma unroll
  for (int i = 0; i < 4; ++i)
#pragma unroll
    for (int j = 0; j < 4; ++j) acc[i][j] = zero4;

  const size_t Abase = (size_t)(bm * 128) * K;
  const size_t Bbase = (size_t)(bn * 128) * K;

  for (int kt = 0; kt < K; kt += 32) {
#pragma unroll
    for (int c = 0; c < 2; ++c) {
      const int grp = wave * 2 + c;
      const int row = grp * 16 + srow;
      const u16* gA = A + Abase + (size_t)row * K + kt + schunk * 8;
      const u16* gB = B + Bbase + (size_t)row * K + kt + schunk * 8;
      async_copy16(gA, As + grp * 512 + lane * 8);
      async_copy16(gB, Bs + grp * 512 + lane * 8);
    }
    __syncthreads();

    s16x8 af[4], bf[4];
#pragma unroll
    for (int mi = 0; mi < 4; ++mi) {
      const int row = wr * 64 + mi * 16 + l15;
      af[mi] = *(const s16x8*)(As + row * 32 + (quad ^ fsw) * 8);
    }
#pragma unroll
    for (int ni = 0; ni < 4; ++ni) {
      const int row = wc * 64 + ni * 16 + l15;
      bf[ni] = *(const s16x8*)(Bs + row * 32 + (quad ^ fsw) * 8);
    }
#pragma unroll
    for (int mi = 0; mi < 4; ++mi)
#pragma unroll
      for (int ni = 0; ni < 4; ++ni)
        acc[mi][ni] = __builtin_amdgcn_mfma_f32_16x16x32_bf16(af[mi], bf[ni], acc[mi][ni], 0, 0, 0);
    __syncthreads();
  }

#pragma unroll
  for (int mi = 0; mi < 4; ++mi) {
#pragma unroll
    for (int ni = 0; ni < 4; ++ni) {
      const int gm0 = bm * 128 + wr * 64 + mi * 16 + quad * 4;
      const int gn  = bn * 128 + wc * 64 + ni * 16 + l15;
#pragma unroll
      for (int r = 0; r < 4; ++r) {
        const size_t idx = (size_t)(gm0 + r) * N + gn;
        if (OUT_BF16) ((u16*)C)[idx] = f2bf(acc[mi][ni][r]);
        else          ((float*)C)[idx] = acc[mi][ni][r];
      }
    }
  }
}

// ---------------- RoPE + split + layout change (vectorized x4) ----------------
__global__ void rope_split(const u16* __restrict__ qkv, u16* __restrict__ Q,
                           u16* __restrict__ Kb, u16* __restrict__ Vt) {
  const int tok = blockIdx.x;          // 0..4095
  const int b = tok >> 11, l = tok & 2047;
  const float pos = (float)l;
  const float SF = 1.1902380714238083f;          // sqrt(1 + log(32)/log(4096))
  const float QSCALE = 0.10206207261596575f;     // 96^-0.5
  const size_t base = (size_t)tok * 9216;
  for (int i = threadIdx.x; i < 768; i += 256) {
    const int g = i * 4;
    const int h = g / 96, d0 = g - h * 96;       // d0 multiple of 4; halves aligned
    const ushort4 qv4 = *(const ushort4*)(qkv + base + g);
    const ushort4 kv4 = *(const ushort4*)(qkv + base + 3072 + g);
    const ushort4 vv4 = *(const ushort4*)(qkv + base + 6144 + g);
    const int dp0    = (d0 < 48) ? d0 + 48 : d0 - 48;
    const float sgn  = (d0 < 48) ? -1.0f : 1.0f;
    const ushort4 qp4 = *(const ushort4*)(qkv + base + h * 96 + dp0);
    const ushort4 kp4 = *(const ushort4*)(qkv + base + 3072 + h * 96 + dp0);
    const int fi0 = (d0 < 48) ? d0 : d0 - 48;
    const int bh = b * 32 + h;
    ushort4 qo, ko;
    const u16* qvp = (const u16*)&qv4; const u16* kvp = (const u16*)&kv4;
    const u16* qpp = (const u16*)&qp4; const u16* kpp = (const u16*)&kp4;
    const u16* vvp = (const u16*)&vv4;
    u16* qop = (u16*)&qo; u16* kop = (u16*)&ko;
#pragma unroll
    for (int e = 0; e < 4; ++e) {
      const float inv = exp2f(-13.287712379549449f * ((float)(fi0 + e) * (1.0f / 48.0f)));
      const float ang = pos * inv;
      float s, c;
      sincosf(ang, &s, &c);
      c *= SF; s *= SF;
      const float qout = bf2f(qvp[e]) * c + bf2f(qpp[e]) * sgn * s;
      const float kout = bf2f(kvp[e]) * c + bf2f(kpp[e]) * sgn * s;
      qop[e] = f2bf(qout * QSCALE);
      kop[e] = f2bf(kout);
      Vt[((size_t)bh * 96 + d0 + e) * 2048 + l] = vvp[e];
    }
    *(ushort4*)(Q  + ((size_t)bh * 2048 + l) * 96 + d0) = qo;
    *(ushort4*)(Kb + ((size_t)bh * 2048 + l) * 96 + d0) = ko;
  }
}

// ---------------- flash attention (causal), LDS-staged K/V, 2-phase pipeline ----------------
// grid (32 qblocks, 64 bh), 256 thr = 4 waves; wave w owns q rows qb*64+w*16..+15.
// Per 64-key tile: K and V are staged block-wide into LDS double-buffers via
// global_load_lds (issued BEFORE compute of the current tile; __syncthreads'
// implicit vmcnt(0) drain at tile end lands after a full compute phase of overlap).
//   K tile [64][104] u16: 208B rows (12 data chunks + 1 pad chunk) -> ds_read_b128
//     bank spread is even (8-deep = LDS floor); read addr stays row*104+c*32+quad*8.
//   V tile [96][64] u16: 128B rows, chunk XOR-swizzle slot=kc^(d&7) applied on the
//     *global source* during staging (LDS dest must stay linear) and on the read.
// Softmax / P-through-LDS / causal skipping / heavy-first order unchanged from R0.
__global__ __launch_bounds__(256, 2)
void attn(const u16* __restrict__ Q, const u16* __restrict__ Kb,
          const u16* __restrict__ Vt, u16* __restrict__ ctx) {
  const int qb = 31 - blockIdx.x;   // heavy blocks first
  const int bh = blockIdx.y;        // 0..63
  const int tid = threadIdx.x, lane = tid & 63, wave = tid >> 6;
  const int l15 = lane & 15, quad = lane >> 4;

  __shared__ alignas(16) u16 Kl[2][64 * 104];   // 2 x 13312 B
  __shared__ alignas(16) u16 Vl[2][96 * 64];    // 2 x 12288 B
  __shared__ alignas(16) u16 Pl[4][16][80];     // per-wave P tile, rows padded to 160B

  const size_t hbase = (size_t)bh * 2048 * 96;
  const int q0 = qb * 64 + wave * 16;

  s16x8 aq[3];
#pragma unroll
  for (int c = 0; c < 3; ++c)
    aq[c] = *(const s16x8*)(Q + hbase + (size_t)(q0 + l15) * 96 + c * 32 + quad * 8);

  float m_[4] = {-1e30f, -1e30f, -1e30f, -1e30f};
  float l_[4] = {0.f, 0.f, 0.f, 0.f};
  f32x4 o[6];
  const f32x4 zero4 = {0.f, 0.f, 0.f, 0.f};
#pragma unroll
  for (int d = 0; d < 6; ++d) o[d] = zero4;

  // Stage one 64-key K/V tile into LDS buffer `buf` (all 4 waves cooperate).
  auto stage = [&](int buf, int kb) {
    const int k0 = kb * 64;
    // K: 64 rows x 13 chunks of 16B (last chunk = pad, sourced from a safe in-row addr)
    for (int j = wave; j < 13; j += 4) {
      const int id = j * 64 + lane;          // 0..831
      const int k  = id / 13;
      const int cc = id - k * 13;
      const u16* src = Kb + hbase + (size_t)(k0 + k) * 96 + (cc < 12 ? cc * 8 : 0);
      async_copy16(src, &Kl[buf][j * 512 + lane * 8]);
    }
    // V: 96 rows x 8 chunks of 16B, XOR-swizzled source
    for (int j = wave; j < 12; j += 4) {
      const int id = j * 64 + lane;          // 0..767
      const int d  = id >> 3;
      const int lc = (id & 7) ^ (d & 7);
      const u16* src = Vt + ((size_t)bh * 96 + d) * 2048 + k0 + lc * 8;
      async_copy16(src, &Vl[buf][j * 512 + lane * 8]);
    }
  };

  stage(0, 0);
  __syncthreads();          // drains vmcnt(0): tile 0 landed
  int cur = 0;

  for (int kb = 0; kb <= qb; ++kb) {
    if (kb < qb) stage(cur ^ 1, kb + 1);     // prefetch next tile; flies under compute
    const int k0 = kb * 64;
    const bool last = (kb == qb);
    const int nsub   = last ? (wave + 1) : 4;        // QK^T subtiles needed
    const int nchunk = last ? ((wave >> 1) + 1) : 2; // PV 32-key chunks needed
    const int nsw    = nchunk * 2;                   // P subtiles that must land in LDS

    f32x4 s[4];
#pragma unroll
    for (int sub = 0; sub < 4; ++sub) {
      if (sub < nsub) {
        const u16* kr = &Kl[cur][(sub * 16 + l15) * 104 + quad * 8];
        const s16x8 b0 = *(const s16x8*)(kr);
        const s16x8 b1 = *(const s16x8*)(kr + 32);
        const s16x8 b2 = *(const s16x8*)(kr + 64);
        f32x4 t = __builtin_amdgcn_mfma_f32_16x16x32_bf16(aq[0], b0, zero4, 0, 0, 0);
        t = __builtin_amdgcn_mfma_f32_16x16x32_bf16(aq[1], b1, t, 0, 0, 0);
        t = __builtin_amdgcn_mfma_f32_16x16x32_bf16(aq[2], b2, t, 0, 0, 0);
        s[sub] = t;
      } else {
        s[sub] = (f32x4){-1e30f, -1e30f, -1e30f, -1e30f};
      }
    }

    // causal mask only ever bites in the diagonal block
    if (last) {
#pragma unroll
      for (int sub = 0; sub < 4; ++sub)
#pragma unroll
        for (int r = 0; r < 4; ++r) {
          const int row = q0 + quad * 4 + r;
          const int col = k0 + sub * 16 + l15;
          if (col > row) s[sub][r] = -1e30f;
        }
    }

    // online softmax (rows spread over 16 lanes; offsets 1..8 stay in-group)
    float alpha[4];
#pragma unroll
    for (int r = 0; r < 4; ++r) {
      float mx = fmaxf(fmaxf(s[0][r], s[1][r]), fmaxf(s[2][r], s[3][r]));
#pragma unroll
      for (int off = 8; off >= 1; off >>= 1) mx = fmaxf(mx, __shfl_xor(mx, off));
      const float mn = fmaxf(m_[r], mx);
      alpha[r] = __expf(m_[r] - mn);
      const float p0 = __expf(s[0][r] - mn);
      const float p1 = __expf(s[1][r] - mn);
      const float p2 = __expf(s[2][r] - mn);
      const float p3 = __expf(s[3][r] - mn);
      s[0][r] = p0; s[1][r] = p1; s[2][r] = p2; s[3][r] = p3;
      float rs = (p0 + p1) + (p2 + p3);
#pragma unroll
      for (int off = 8; off >= 1; off >>= 1) rs += __shfl_xor(rs, off);
      l_[r] = l_[r] * alpha[r] + rs;
      m_[r] = mn;
    }
#pragma unroll
    for (int d = 0; d < 6; ++d)
#pragma unroll
      for (int r = 0; r < 4; ++r) o[d][r] *= alpha[r];

    // P: C-layout -> per-wave LDS (row stride 160B; intra-wave lgkmcnt ordering only)
#pragma unroll
    for (int sub = 0; sub < 4; ++sub) {
      if (sub < nsw) {
#pragma unroll
        for (int r = 0; r < 4; ++r)
          Pl[wave][quad * 4 + r][sub * 16 + l15] = f2bf(s[sub][r]);
      }
    }

    // PV: A-fragment from LDS P, B-fragment from staged V tile
#pragma unroll
    for (int c = 0; c < 2; ++c) {
      if (c < nchunk) {
        const s16x8 ap = *(const s16x8*)(&Pl[wave][l15][c * 32 + quad * 8]);
#pragma unroll
        for (int dblk = 0; dblk < 6; ++dblk) {
          const int d = dblk * 16 + l15;
          const s16x8 bv = *(const s16x8*)(&Vl[cur][d * 64 + (((c * 4 + quad) ^ (d & 7)) * 8)]);
          o[dblk] = __builtin_amdgcn_mfma_f32_16x16x32_bf16(ap, bv, o[dblk], 0, 0, 0);
        }
      }
    }

    __syncthreads();   // implicit vmcnt(0)+lgkmcnt(0) drain: next tile landed, cur free
    cur ^= 1;
  }

  // write ctx[b, q, h*96 + d] bf16
  const int b = bh >> 5, h = bh & 31;
  float invl[4];
#pragma unroll
  for (int r = 0; r < 4; ++r) invl[r] = 1.0f / l_[r];
#pragma unroll
  for (int d = 0; d < 6; ++d)
#pragma unroll
    for (int r = 0; r < 4; ++r) {
      const int row = q0 + quad * 4 + r;
      ctx[((size_t)(b * 2048 + row)) * 3072 + h * 96 + d * 16 + l15] = f2bf(o[d][r] * invl[r]);
    }
}

// ---------------- launch ----------------
extern "C" void kernel_launch(void* const* d_in, const int* in_sizes, int n_in,
                              void* d_out, int out_size, void* d_ws, size_t ws_size,
                              hipStream_t stream) {
  const float* x    = (const float*)d_in[0];   // [2,2048,3072]
  const float* Wqkv = (const float*)d_in[1];   // [9216,3072]
  const float* Wo   = (const float*)d_in[2];   // [3072,3072]
  float* out = (float*)d_out;                  // [2,2048,3072] fp32

  char* ws = (char*)d_ws;
  u16* wq_b  = (u16*)(ws);                  // 56,623,104 B
  u16* wo_b  = (u16*)(ws + 56623104);       // 18,874,368 B
  u16* x_b   = (u16*)(ws + 75497472);       // 25,165,824 B
  u16* qkv_b = (u16*)(ws + 100663296);      // 75,497,472 B
  u16* K_b   = (u16*)(ws + 176160768);      // 25,165,824 B
  u16* Vt_b  = (u16*)(ws + 201326592);      // 25,165,824 B
  u16* Q_b   = x_b;                         // alias: x dead after GEMM1
  u16* ctx_b = qkv_b;                       // alias: qkv dead after rope_split

  cvt_f32_bf16<<<27648, 256, 0, stream>>>(Wqkv, wq_b, 28311552 / 4);
  cvt_f32_bf16<<<9216,  256, 0, stream>>>(Wo,   wo_b,  9437184 / 4);
  cvt_f32_bf16<<<12288, 256, 0, stream>>>(x,    x_b,  12582912 / 4);

  // qkv = x @ Wqkv^T   [4096 x 9216], K=3072
  gemm_nt<true><<<dim3(32, 72), 256, 0, stream>>>(x_b, wq_b, (void*)qkv_b, 4096, 9216, 3072);

  rope_split<<<4096, 256, 0, stream>>>(qkv_b, Q_b, K_b, Vt_b);

  attn<<<dim3(32, 64), 256, 0, stream>>>(Q_b, K_b, Vt_b, ctx_b);

  // out = ctx @ Wo^T   [4096 x 3072], K=3072, fp32 out
  gemm_nt<false><<<dim3(32, 24), 256, 0, stream>>>(ctx_b, wo_b, (void*)out, 4096, 3072, 3072);
}

// Round 3
// 908.007 us; speedup vs baseline: 1.3183x; 1.1083x over previous
//
#include <hip/hip_runtime.h>
#include <cstdint>

typedef short s16x8 __attribute__((ext_vector_type(8)));
typedef float f32x4 __attribute__((ext_vector_type(4)));
typedef unsigned short u16;

#define DEV static __device__ __forceinline__

DEV float bf2f(u16 b) {
  union { unsigned u; float f; } v; v.u = ((unsigned)b) << 16; return v.f;
}
DEV u16 f2bf(float f) {
  union { float f; unsigned u; } v; v.f = f;
  unsigned r = 0x7fffu + ((v.u >> 16) & 1u);   // RNE
  return (u16)((v.u + r) >> 16);
}

typedef __attribute__((address_space(3))) void lds_void_t;
typedef const __attribute__((address_space(1))) void glob_void_t;

DEV void async_copy16(const void* g, void* l) {
  __builtin_amdgcn_global_load_lds(
      (glob_void_t*)(uintptr_t)g,
      (lds_void_t*)(uint32_t)(uintptr_t)l,
      16, 0, 0);
}

// ---------------- fp32 -> bf16 convert (vectorized x4) ----------------
__global__ void cvt_f32_bf16(const float* __restrict__ in, u16* __restrict__ out, int n4) {
  int i = blockIdx.x * 256 + threadIdx.x;
  if (i < n4) {
    const float4 v = reinterpret_cast<const float4*>(in)[i];
    ushort4 o;
    o.x = f2bf(v.x); o.y = f2bf(v.y); o.z = f2bf(v.z); o.w = f2bf(v.w);
    reinterpret_cast<ushort4*>(out)[i] = o;
  }
}

// ---------------- NT GEMM: C[m,n] = sum_k A[m,k]*B[n,k] ----------------
// (unchanged — isolating the attn softmax rewrite this round)
template <bool OUT_BF16>
__global__ __launch_bounds__(256, 2)
void gemm_nt(const u16* __restrict__ A, const u16* __restrict__ B,
             void* __restrict__ C, int M, int N, int K) {
  __shared__ u16 As[128 * 32];
  __shared__ u16 Bs[128 * 32];
  const int tid  = threadIdx.x;
  const int lane = tid & 63;
  const int wave = tid >> 6;
  const int wr = wave >> 1, wc = wave & 1;
  const int l15 = lane & 15, quad = lane >> 4;
  const int bm = blockIdx.x, bn = blockIdx.y;

  const int srow   = lane >> 2;
  const int schunk = (lane & 3) ^ ((srow >> 1) & 3);
  const int fsw    = (l15 >> 1) & 3;

  f32x4 acc[4][4];
  const f32x4 zero4 = {0.f, 0.f, 0.f, 0.f};
#pragma unroll
  for (int i = 0; i < 4; ++i)
#pragma unroll
    for (int j = 0; j < 4; ++j) acc[i][j] = zero4;

  const size_t Abase = (size_t)(bm * 128) * K;
  const size_t Bbase = (size_t)(bn * 128) * K;

  for (int kt = 0; kt < K; kt += 32) {
#pragma unroll
    for (int c = 0; c < 2; ++c) {
      const int grp = wave * 2 + c;
      const int row = grp * 16 + srow;
      const u16* gA = A + Abase + (size_t)row * K + kt + schunk * 8;
      const u16* gB = B + Bbase + (size_t)row * K + kt + schunk * 8;
      async_copy16(gA, As + grp * 512 + lane * 8);
      async_copy16(gB, Bs + grp * 512 + lane * 8);
    }
    __syncthreads();

    s16x8 af[4], bf[4];
#pragma unroll
    for (int mi = 0; mi < 4; ++mi) {
      const int row = wr * 64 + mi * 16 + l15;
      af[mi] = *(const s16x8*)(As + row * 32 + (quad ^ fsw) * 8);
    }
#pragma unroll
    for (int ni = 0; ni < 4; ++ni) {
      const int row = wc * 64 + ni * 16 + l15;
      bf[ni] = *(const s16x8*)(Bs + row * 32 + (quad ^ fsw) * 8);
    }
#pragma unroll
    for (int mi = 0; mi < 4; ++mi)
#pragma unroll
      for (int ni = 0; ni < 4; ++ni)
        acc[mi][ni] = __builtin_amdgcn_mfma_f32_16x16x32_bf16(af[mi], bf[ni], acc[mi][ni], 0, 0, 0);
    __syncthreads();
  }

#pragma unroll
  for (int mi = 0; mi < 4; ++mi) {
#pragma unroll
    for (int ni = 0; ni < 4; ++ni) {
      const int gm0 = bm * 128 + wr * 64 + mi * 16 + quad * 4;
      const int gn  = bn * 128 + wc * 64 + ni * 16 + l15;
#pragma unroll
      for (int r = 0; r < 4; ++r) {
        const size_t idx = (size_t)(gm0 + r) * N + gn;
        if (OUT_BF16) ((u16*)C)[idx] = f2bf(acc[mi][ni][r]);
        else          ((float*)C)[idx] = acc[mi][ni][r];
      }
    }
  }
}

// ---------------- RoPE + split + layout change (vectorized x4) ----------------
__global__ void rope_split(const u16* __restrict__ qkv, u16* __restrict__ Q,
                           u16* __restrict__ Kb, u16* __restrict__ Vt) {
  const int tok = blockIdx.x;          // 0..4095
  const int b = tok >> 11, l = tok & 2047;
  const float pos = (float)l;
  const float SF = 1.1902380714238083f;          // sqrt(1 + log(32)/log(4096))
  const float QSCALE = 0.10206207261596575f;     // 96^-0.5
  const size_t base = (size_t)tok * 9216;
  for (int i = threadIdx.x; i < 768; i += 256) {
    const int g = i * 4;
    const int h = g / 96, d0 = g - h * 96;       // d0 multiple of 4; halves aligned
    const ushort4 qv4 = *(const ushort4*)(qkv + base + g);
    const ushort4 kv4 = *(const ushort4*)(qkv + base + 3072 + g);
    const ushort4 vv4 = *(const ushort4*)(qkv + base + 6144 + g);
    const int dp0    = (d0 < 48) ? d0 + 48 : d0 - 48;
    const float sgn  = (d0 < 48) ? -1.0f : 1.0f;
    const ushort4 qp4 = *(const ushort4*)(qkv + base + h * 96 + dp0);
    const ushort4 kp4 = *(const ushort4*)(qkv + base + 3072 + h * 96 + dp0);
    const int fi0 = (d0 < 48) ? d0 : d0 - 48;
    const int bh = b * 32 + h;
    ushort4 qo, ko;
    const u16* qvp = (const u16*)&qv4; const u16* kvp = (const u16*)&kv4;
    const u16* qpp = (const u16*)&qp4; const u16* kpp = (const u16*)&kp4;
    const u16* vvp = (const u16*)&vv4;
    u16* qop = (u16*)&qo; u16* kop = (u16*)&ko;
#pragma unroll
    for (int e = 0; e < 4; ++e) {
      const float inv = exp2f(-13.287712379549449f * ((float)(fi0 + e) * (1.0f / 48.0f)));
      const float ang = pos * inv;
      float s, c;
      sincosf(ang, &s, &c);
      c *= SF; s *= SF;
      const float qout = bf2f(qvp[e]) * c + bf2f(qpp[e]) * sgn * s;
      const float kout = bf2f(kvp[e]) * c + bf2f(kpp[e]) * sgn * s;
      qop[e] = f2bf(qout * QSCALE);
      kop[e] = f2bf(kout);
      Vt[((size_t)bh * 96 + d0 + e) * 2048 + l] = vvp[e];
    }
    *(ushort4*)(Q  + ((size_t)bh * 2048 + l) * 96 + d0) = qo;
    *(ushort4*)(Kb + ((size_t)bh * 2048 + l) * 96 + d0) = ko;
  }
}

// ---------------- flash attention (causal), LDS-staged K/V, swapped-QK^T softmax ----------------
// grid (32 qblocks, 64 bh), 256 thr = 4 waves; wave w owns q rows qb*64+w*16..+15.
// K/V staged block-wide into LDS double-buffers via global_load_lds (prefetch issued
// before compute; __syncthreads' vmcnt(0) drain lands after a full compute phase).
// QK^T computed SWAPPED: mfma(K,Q) -> D[row=k][col=q]; lane l15 owns one q-row with
// 16 P-values in registers. Softmax = in-register tree + 2 shfl_xor (16,32).
// P -> PV A-fragment via v_cvt_pk_bf16_f32 + 8 ds_bpermute/chunk (no P LDS buffer).
// LDS 51200 B -> 3 blocks/CU.
__global__ __launch_bounds__(256, 3)
void attn(const u16* __restrict__ Q, const u16* __restrict__ Kb,
          const u16* __restrict__ Vt, u16* __restrict__ ctx) {
  const int qb = 31 - blockIdx.x;   // heavy blocks first
  const int bh = blockIdx.y;        // 0..63
  const int tid = threadIdx.x, lane = tid & 63, wave = tid >> 6;
  const int l15 = lane & 15, quad = lane >> 4;

  __shared__ alignas(16) u16 Kl[2][64 * 104];   // 2 x 13312 B
  __shared__ alignas(16) u16 Vl[2][96 * 64];    // 2 x 12288 B

  const size_t hbase = (size_t)bh * 2048 * 96;
  const int q0 = qb * 64 + wave * 16;

  s16x8 aq[3];
#pragma unroll
  for (int c = 0; c < 3; ++c)
    aq[c] = *(const s16x8*)(Q + hbase + (size_t)(q0 + l15) * 96 + c * 32 + quad * 8);

  float m_ = -1e30f, l_ = 0.f;        // per-lane: q-row q0+l15 (replicated across quads)
  f32x4 o[6];
  const f32x4 zero4 = {0.f, 0.f, 0.f, 0.f};
#pragma unroll
  for (int d = 0; d < 6; ++d) o[d] = zero4;

  // Stage one 64-key K/V tile into LDS buffer `buf` (all 4 waves cooperate).
  auto stage = [&](int buf, int kb) {
    const int k0 = kb * 64;
    // K: 64 rows x 13 chunks of 16B (last chunk = pad, sourced from a safe in-row addr)
    for (int j = wave; j < 13; j += 4) {
      const int id = j * 64 + lane;          // 0..831
      const int k  = id / 13;
      const int cc = id - k * 13;
      const u16* src = Kb + hbase + (size_t)(k0 + k) * 96 + (cc < 12 ? cc * 8 : 0);
      async_copy16(src, &Kl[buf][j * 512 + lane * 8]);
    }
    // V: 96 rows x 8 chunks of 16B, XOR-swizzled source
    for (int j = wave; j < 12; j += 4) {
      const int id = j * 64 + lane;          // 0..767
      const int d  = id >> 3;
      const int lc = (id & 7) ^ (d & 7);
      const u16* src = Vt + ((size_t)bh * 96 + d) * 2048 + k0 + lc * 8;
      async_copy16(src, &Vl[buf][j * 512 + lane * 8]);
    }
  };

  stage(0, 0);
  __syncthreads();          // drains vmcnt(0): tile 0 landed
  int cur = 0;

  // bpermute addressing for the P redistribution (derived & element-checked):
  // target lane (l15,quad), chunk c, reg g needs pk[2c + (quad>=2)][g&1]
  // from lane l15 + 16*((quad&1)*2 + (g>>1)).
  const int addrA = (l15 + (quad & 1) * 32) * 4;   // for g = 0,1
  const int addrB = addrA + 64;                    // for g = 2,3 (+16 lanes)
  const bool hb = (quad >= 2);

  for (int kb = 0; kb <= qb; ++kb) {
    if (kb < qb) stage(cur ^ 1, kb + 1);     // prefetch next tile; flies under compute
    const int k0 = kb * 64;
    const bool last = (kb == qb);
    const int nsub   = last ? (wave + 1) : 4;        // QK^T subtiles needed
    const int nchunk = last ? ((wave >> 1) + 1) : 2; // PV 32-key chunks needed

    // QK^T swapped: s[sub][r] = P[q = q0+l15][k = k0 + sub*16 + quad*4 + r]
    f32x4 s[4];
#pragma unroll
    for (int sub = 0; sub < 4; ++sub) {
      if (sub < nsub) {
        const u16* kr = &Kl[cur][(sub * 16 + l15) * 104 + quad * 8];
        const s16x8 b0 = *(const s16x8*)(kr);
        const s16x8 b1 = *(const s16x8*)(kr + 32);
        const s16x8 b2 = *(const s16x8*)(kr + 64);
        f32x4 t = __builtin_amdgcn_mfma_f32_16x16x32_bf16(b0, aq[0], zero4, 0, 0, 0);
        t = __builtin_amdgcn_mfma_f32_16x16x32_bf16(b1, aq[1], t, 0, 0, 0);
        t = __builtin_amdgcn_mfma_f32_16x16x32_bf16(b2, aq[2], t, 0, 0, 0);
        s[sub] = t;
      } else {
        s[sub] = (f32x4){-1e30f, -1e30f, -1e30f, -1e30f};
      }
    }

    // causal mask only ever bites in the diagonal block
    if (last) {
      const int q = q0 + l15;
#pragma unroll
      for (int sub = 0; sub < 4; ++sub)
#pragma unroll
        for (int r = 0; r < 4; ++r) {
          const int k = k0 + sub * 16 + quad * 4 + r;
          if (k > q) s[sub][r] = -1e30f;
        }
    }

    // online softmax — in-register row reduce + 2 shfl_xor across the 4 quads
    float mx = s[0][0];
#pragma unroll
    for (int sub = 0; sub < 4; ++sub)
#pragma unroll
      for (int r = 0; r < 4; ++r) mx = fmaxf(mx, s[sub][r]);
    mx = fmaxf(mx, __shfl_xor(mx, 16));
    mx = fmaxf(mx, __shfl_xor(mx, 32));
    const float mn = fmaxf(m_, mx);
    const float al = __expf(m_ - mn);
    m_ = mn;
#pragma unroll
    for (int sub = 0; sub < 4; ++sub)
#pragma unroll
      for (int r = 0; r < 4; ++r) s[sub][r] = __expf(s[sub][r] - mn);
    float rs = (((s[0][0] + s[0][1]) + (s[0][2] + s[0][3])) +
                ((s[1][0] + s[1][1]) + (s[1][2] + s[1][3]))) +
               (((s[2][0] + s[2][1]) + (s[2][2] + s[2][3])) +
                ((s[3][0] + s[3][1]) + (s[3][2] + s[3][3])));
    rs += __shfl_xor(rs, 16);
    rs += __shfl_xor(rs, 32);
    l_ = l_ * al + rs;

    // redistribute alpha to the o accumulator layout (q = quad*4 + r lives in lane quad*4+r)
    float alr[4];
#pragma unroll
    for (int r = 0; r < 4; ++r)
      alr[r] = __int_as_float(__builtin_amdgcn_ds_bpermute((quad * 4 + r) * 4,
                                                           __float_as_int(al)));
#pragma unroll
    for (int d = 0; d < 6; ++d)
#pragma unroll
      for (int r = 0; r < 4; ++r) o[d][r] *= alr[r];

    // pack P pairs to bf16x2: pk[sub][t] = (bf16(s[sub][2t]), bf16(s[sub][2t+1]))
    unsigned pk[4][2];
#pragma unroll
    for (int sub = 0; sub < 4; ++sub) {
      asm("v_cvt_pk_bf16_f32 %0, %1, %2" : "=v"(pk[sub][0]) : "v"(s[sub][0]), "v"(s[sub][1]));
      asm("v_cvt_pk_bf16_f32 %0, %1, %2" : "=v"(pk[sub][1]) : "v"(s[sub][2]), "v"(s[sub][3]));
    }

    // PV: A-fragment assembled in-register via ds_bpermute; B-fragment from staged V
#pragma unroll
    for (int c = 0; c < 2; ++c) {
      if (c < nchunk) {
        const int a00 = __builtin_amdgcn_ds_bpermute(addrA, (int)pk[c * 2][0]);
        const int a01 = __builtin_amdgcn_ds_bpermute(addrA, (int)pk[c * 2][1]);
        const int a10 = __builtin_amdgcn_ds_bpermute(addrA, (int)pk[c * 2 + 1][0]);
        const int a11 = __builtin_amdgcn_ds_bpermute(addrA, (int)pk[c * 2 + 1][1]);
        const int b00 = __builtin_amdgcn_ds_bpermute(addrB, (int)pk[c * 2][0]);
        const int b01 = __builtin_amdgcn_ds_bpermute(addrB, (int)pk[c * 2][1]);
        const int b10 = __builtin_amdgcn_ds_bpermute(addrB, (int)pk[c * 2 + 1][0]);
        const int b11 = __builtin_amdgcn_ds_bpermute(addrB, (int)pk[c * 2 + 1][1]);
        union { s16x8 v; int u[4]; } ap;
        ap.u[0] = hb ? a10 : a00;
        ap.u[1] = hb ? a11 : a01;
        ap.u[2] = hb ? b10 : b00;
        ap.u[3] = hb ? b11 : b01;
#pragma unroll
        for (int dblk = 0; dblk < 6; ++dblk) {
          const int d = dblk * 16 + l15;
          const s16x8 bv = *(const s16x8*)(&Vl[cur][d * 64 + (((c * 4 + quad) ^ (d & 7)) * 8)]);
          o[dblk] = __builtin_amdgcn_mfma_f32_16x16x32_bf16(ap.v, bv, o[dblk], 0, 0, 0);
        }
      }
    }

    __syncthreads();   // implicit vmcnt(0)+lgkmcnt(0) drain: next tile landed, cur free
    cur ^= 1;
  }

  // write ctx[b, q, h*96 + d] bf16 (o layout: row q = quad*4+r, col d = dblk*16+l15)
  const int b = bh >> 5, h = bh & 31;
  float invl[4];
#pragma unroll
  for (int r = 0; r < 4; ++r) {
    const int v = __builtin_amdgcn_ds_bpermute((quad * 4 + r) * 4, __float_as_int(l_));
    invl[r] = 1.0f / __int_as_float(v);
  }
#pragma unroll
  for (int d = 0; d < 6; ++d)
#pragma unroll
    for (int r = 0; r < 4; ++r) {
      const int row = q0 + quad * 4 + r;
      ctx[((size_t)(b * 2048 + row)) * 3072 + h * 96 + d * 16 + l15] = f2bf(o[d][r] * invl[r]);
    }
}

// ---------------- launch ----------------
extern "C" void kernel_launch(void* const* d_in, const int* in_sizes, int n_in,
                              void* d_out, int out_size, void* d_ws, size_t ws_size,
                              hipStream_t stream) {
  const float* x    = (const float*)d_in[0];   // [2,2048,3072]
  const float* Wqkv = (const float*)d_in[1];   // [9216,3072]
  const float* Wo   = (const float*)d_in[2];   // [3072,3072]
  float* out = (float*)d_out;                  // [2,2048,3072] fp32

  char* ws = (char*)d_ws;
  u16* wq_b  = (u16*)(ws);                  // 56,623,104 B
  u16* wo_b  = (u16*)(ws + 56623104);       // 18,874,368 B
  u16* x_b   = (u16*)(ws + 75497472);       // 25,165,824 B
  u16* qkv_b = (u16*)(ws + 100663296);      // 75,497,472 B
  u16* K_b   = (u16*)(ws + 176160768);      // 25,165,824 B
  u16* Vt_b  = (u16*)(ws + 201326592);      // 25,165,824 B
  u16* Q_b   = x_b;                         // alias: x dead after GEMM1
  u16* ctx_b = qkv_b;                       // alias: qkv dead after rope_split

  cvt_f32_bf16<<<27648, 256, 0, stream>>>(Wqkv, wq_b, 28311552 / 4);
  cvt_f32_bf16<<<9216,  256, 0, stream>>>(Wo,   wo_b,  9437184 / 4);
  cvt_f32_bf16<<<12288, 256, 0, stream>>>(x,    x_b,  12582912 / 4);

  // qkv = x @ Wqkv^T   [4096 x 9216], K=3072
  gemm_nt<true><<<dim3(32, 72), 256, 0, stream>>>(x_b, wq_b, (void*)qkv_b, 4096, 9216, 3072);

  rope_split<<<4096, 256, 0, stream>>>(qkv_b, Q_b, K_b, Vt_b);

  attn<<<dim3(32, 64), 256, 0, stream>>>(Q_b, K_b, Vt_b, ctx_b);

  // out = ctx @ Wo^T   [4096 x 3072], K=3072, fp32 out
  gemm_nt<false><<<dim3(32, 24), 256, 0, stream>>>(ctx_b, wo_b, (void*)out, 4096, 3072, 3072);
}

// Round 4
// 878.265 us; speedup vs baseline: 1.3630x; 1.0339x over previous
//
#include <hip/hip_runtime.h>
#include <cstdint>

typedef short s16x8 __attribute__((ext_vector_type(8)));
typedef float f32x4 __attribute__((ext_vector_type(4)));
typedef unsigned short u16;

#define DEV static __device__ __forceinline__

DEV float bf2f(u16 b) {
  union { unsigned u; float f; } v; v.u = ((unsigned)b) << 16; return v.f;
}
DEV u16 f2bf(float f) {
  union { float f; unsigned u; } v; v.f = f;
  unsigned r = 0x7fffu + ((v.u >> 16) & 1u);   // RNE
  return (u16)((v.u + r) >> 16);
}

typedef __attribute__((address_space(3))) void lds_void_t;
typedef const __attribute__((address_space(1))) void glob_void_t;

DEV void async_copy16(const void* g, void* l) {
  __builtin_amdgcn_global_load_lds(
      (glob_void_t*)(uintptr_t)g,
      (lds_void_t*)(uint32_t)(uintptr_t)l,
      16, 0, 0);
}

// ---------------- fp32 -> bf16 convert (vectorized x4) ----------------
__global__ void cvt_f32_bf16(const float* __restrict__ in, u16* __restrict__ out, int n4) {
  int i = blockIdx.x * 256 + threadIdx.x;
  if (i < n4) {
    const float4 v = reinterpret_cast<const float4*>(in)[i];
    ushort4 o;
    o.x = f2bf(v.x); o.y = f2bf(v.y); o.z = f2bf(v.z); o.w = f2bf(v.w);
    reinterpret_cast<ushort4*>(out)[i] = o;
  }
}

// ---------------- 256x256 NT GEMM, phase-split schedule ----------------
// C[m,n] = sum_k A[m,k]*B[n,k]; A,B row-major bf16 K-contiguous.
// BM=BN=256, BK=64, 512 thr = 8 waves (2M x 4N), per-wave 128x64 out, acc[8][4].
// LDS double-buffered 128KB. Per K-tile: 8 global_load_lds issues (next tile)
// BEFORE ds_reads, then 4 phases {4-8 ds_read_b128 -> s_barrier -> setprio(1) ->
// 16 MFMA -> setprio(0)}; one __syncthreads per tile (vmcnt drain lands after a
// full compute phase of overlap).  LDS swizzle: chunk ^= row&7 (16B granularity),
// applied on the GLOBAL SOURCE during staging (LDS dest stays lane-linear, rule
// "both-sides-or-neither") and on the ds_read address — m214-proven involution.
// Grid: 1-D, bijective XCD swizzle (nwg divisible by 8 for our shapes 576/192).
template <bool OUT_BF16>
__global__ __launch_bounds__(512, 2)
void gemm_nt256(const u16* __restrict__ A, const u16* __restrict__ B,
                void* __restrict__ C, int M, int N, int K) {
  __shared__ u16 As[2][256 * 64];   // 2 x 32 KB
  __shared__ u16 Bs[2][256 * 64];   // 2 x 32 KB
  const int tid  = threadIdx.x;
  const int lane = tid & 63;
  const int wave = tid >> 6;
  const int wm = wave >> 2, wn = wave & 3;
  const int l15 = lane & 15, quad = lane >> 4;

  // XCD-aware swizzle: consecutive swz share a B-panel within an XCD's L2
  const int nwg = gridDim.x;
  const int cpx = nwg >> 3;                       // nwg % 8 == 0 for our shapes
  const int swz = (blockIdx.x & 7) * cpx + (blockIdx.x >> 3);
  const int mb  = M >> 8;
  const int bm  = swz % mb, bn = swz / mb;

  f32x4 acc[8][4];
  const f32x4 zero4 = {0.f, 0.f, 0.f, 0.f};
#pragma unroll
  for (int mi = 0; mi < 8; ++mi)
#pragma unroll
    for (int ni = 0; ni < 4; ++ni) acc[mi][ni] = zero4;

  const size_t Abase = (size_t)(bm * 256) * K;
  const size_t Bbase = (size_t)(bn * 256) * K;

  // Stage one 256x64 A-tile + B-tile into LDS buffer `buf` (8 issues/thread).
  auto stage = [&](int buf, int kt) {
#pragma unroll
    for (int j = 0; j < 4; ++j) {
      const int id  = j * 512 + tid;        // 0..2047 = 256 rows x 8 chunks
      const int row = id >> 3;
      const int sc  = ((id & 7) ^ (row & 7)) * 8;
      async_copy16(A + Abase + (size_t)row * K + kt + sc, &As[buf][id * 8]);
    }
#pragma unroll
    for (int j = 0; j < 4; ++j) {
      const int id  = j * 512 + tid;
      const int row = id >> 3;
      const int sc  = ((id & 7) ^ (row & 7)) * 8;
      async_copy16(B + Bbase + (size_t)row * K + kt + sc, &Bs[buf][id * 8]);
    }
  };

  stage(0, 0);
  __syncthreads();            // drains vmcnt(0): tile 0 landed
  int cur = 0;
  const int NT = K >> 6;

  for (int t = 0; t < NT; ++t) {
    if (t + 1 < NT) stage(cur ^ 1, (t + 1) << 6);   // prefetch; flies under 4 phases

    // B-frags for the whole tile (8 x ds_read_b128), reused by all 4 phases
    s16x8 bfr[2][4];
#pragma unroll
    for (int ks = 0; ks < 2; ++ks)
#pragma unroll
      for (int ni = 0; ni < 4; ++ni) {
        const int row = wn * 64 + ni * 16 + l15;
        bfr[ks][ni] = *(const s16x8*)(&Bs[cur][row * 64 + ((ks * 4 + quad) ^ (row & 7)) * 8]);
      }

#pragma unroll
    for (int qd = 0; qd < 4; ++qd) {
      s16x8 afr[2][2];
#pragma unroll
      for (int ks = 0; ks < 2; ++ks)
#pragma unroll
        for (int mm = 0; mm < 2; ++mm) {
          const int row = wm * 128 + (qd * 2 + mm) * 16 + l15;
          afr[ks][mm] = *(const s16x8*)(&As[cur][row * 64 + ((ks * 4 + quad) ^ (row & 7)) * 8]);
        }
      __builtin_amdgcn_s_barrier();
      __builtin_amdgcn_sched_barrier(0);
      __builtin_amdgcn_s_setprio(1);
#pragma unroll
      for (int ks = 0; ks < 2; ++ks)
#pragma unroll
        for (int mm = 0; mm < 2; ++mm)
#pragma unroll
          for (int ni = 0; ni < 4; ++ni)
            acc[qd * 2 + mm][ni] = __builtin_amdgcn_mfma_f32_16x16x32_bf16(
                afr[ks][mm], bfr[ks][ni], acc[qd * 2 + mm][ni], 0, 0, 0);
      __builtin_amdgcn_s_setprio(0);
    }
    __syncthreads();          // vmcnt(0)+lgkmcnt(0) drain: next tile landed, cur free
    cur ^= 1;
  }

#pragma unroll
  for (int mi = 0; mi < 8; ++mi) {
#pragma unroll
    for (int ni = 0; ni < 4; ++ni) {
      const int gm0 = bm * 256 + wm * 128 + mi * 16 + quad * 4;
      const int gn  = bn * 256 + wn * 64 + ni * 16 + l15;
#pragma unroll
      for (int r = 0; r < 4; ++r) {
        const size_t idx = (size_t)(gm0 + r) * N + gn;
        if (OUT_BF16) ((u16*)C)[idx] = f2bf(acc[mi][ni][r]);
        else          ((float*)C)[idx] = acc[mi][ni][r];
      }
    }
  }
}

// ---------------- RoPE + split + layout change (vectorized x4) ----------------
__global__ void rope_split(const u16* __restrict__ qkv, u16* __restrict__ Q,
                           u16* __restrict__ Kb, u16* __restrict__ Vt) {
  const int tok = blockIdx.x;          // 0..4095
  const int b = tok >> 11, l = tok & 2047;
  const float pos = (float)l;
  const float SF = 1.1902380714238083f;          // sqrt(1 + log(32)/log(4096))
  const float QSCALE = 0.10206207261596575f;     // 96^-0.5
  const size_t base = (size_t)tok * 9216;
  for (int i = threadIdx.x; i < 768; i += 256) {
    const int g = i * 4;
    const int h = g / 96, d0 = g - h * 96;       // d0 multiple of 4; halves aligned
    const ushort4 qv4 = *(const ushort4*)(qkv + base + g);
    const ushort4 kv4 = *(const ushort4*)(qkv + base + 3072 + g);
    const ushort4 vv4 = *(const ushort4*)(qkv + base + 6144 + g);
    const int dp0    = (d0 < 48) ? d0 + 48 : d0 - 48;
    const float sgn  = (d0 < 48) ? -1.0f : 1.0f;
    const ushort4 qp4 = *(const ushort4*)(qkv + base + h * 96 + dp0);
    const ushort4 kp4 = *(const ushort4*)(qkv + base + 3072 + h * 96 + dp0);
    const int fi0 = (d0 < 48) ? d0 : d0 - 48;
    const int bh = b * 32 + h;
    ushort4 qo, ko;
    const u16* qvp = (const u16*)&qv4; const u16* kvp = (const u16*)&kv4;
    const u16* qpp = (const u16*)&qp4; const u16* kpp = (const u16*)&kp4;
    const u16* vvp = (const u16*)&vv4;
    u16* qop = (u16*)&qo; u16* kop = (u16*)&ko;
#pragma unroll
    for (int e = 0; e < 4; ++e) {
      const float inv = exp2f(-13.287712379549449f * ((float)(fi0 + e) * (1.0f / 48.0f)));
      const float ang = pos * inv;
      float s, c;
      sincosf(ang, &s, &c);
      c *= SF; s *= SF;
      const float qout = bf2f(qvp[e]) * c + bf2f(qpp[e]) * sgn * s;
      const float kout = bf2f(kvp[e]) * c + bf2f(kpp[e]) * sgn * s;
      qop[e] = f2bf(qout * QSCALE);
      kop[e] = f2bf(kout);
      Vt[((size_t)bh * 96 + d0 + e) * 2048 + l] = vvp[e];
    }
    *(ushort4*)(Q  + ((size_t)bh * 2048 + l) * 96 + d0) = qo;
    *(ushort4*)(Kb + ((size_t)bh * 2048 + l) * 96 + d0) = ko;
  }
}

// ---------------- flash attention (causal), LDS-staged K/V, swapped-QK^T softmax ----------------
// (unchanged from R3 — isolating the GEMM rewrite this round)
__global__ __launch_bounds__(256, 3)
void attn(const u16* __restrict__ Q, const u16* __restrict__ Kb,
          const u16* __restrict__ Vt, u16* __restrict__ ctx) {
  const int qb = 31 - blockIdx.x;   // heavy blocks first
  const int bh = blockIdx.y;        // 0..63
  const int tid = threadIdx.x, lane = tid & 63, wave = tid >> 6;
  const int l15 = lane & 15, quad = lane >> 4;

  __shared__ alignas(16) u16 Kl[2][64 * 104];   // 2 x 13312 B
  __shared__ alignas(16) u16 Vl[2][96 * 64];    // 2 x 12288 B

  const size_t hbase = (size_t)bh * 2048 * 96;
  const int q0 = qb * 64 + wave * 16;

  s16x8 aq[3];
#pragma unroll
  for (int c = 0; c < 3; ++c)
    aq[c] = *(const s16x8*)(Q + hbase + (size_t)(q0 + l15) * 96 + c * 32 + quad * 8);

  float m_ = -1e30f, l_ = 0.f;        // per-lane: q-row q0+l15 (replicated across quads)
  f32x4 o[6];
  const f32x4 zero4 = {0.f, 0.f, 0.f, 0.f};
#pragma unroll
  for (int d = 0; d < 6; ++d) o[d] = zero4;

  // Stage one 64-key K/V tile into LDS buffer `buf` (all 4 waves cooperate).
  auto stage = [&](int buf, int kb) {
    const int k0 = kb * 64;
    // K: 64 rows x 13 chunks of 16B (last chunk = pad, sourced from a safe in-row addr)
    for (int j = wave; j < 13; j += 4) {
      const int id = j * 64 + lane;          // 0..831
      const int k  = id / 13;
      const int cc = id - k * 13;
      const u16* src = Kb + hbase + (size_t)(k0 + k) * 96 + (cc < 12 ? cc * 8 : 0);
      async_copy16(src, &Kl[buf][j * 512 + lane * 8]);
    }
    // V: 96 rows x 8 chunks of 16B, XOR-swizzled source
    for (int j = wave; j < 12; j += 4) {
      const int id = j * 64 + lane;          // 0..767
      const int d  = id >> 3;
      const int lc = (id & 7) ^ (d & 7);
      const u16* src = Vt + ((size_t)bh * 96 + d) * 2048 + k0 + lc * 8;
      async_copy16(src, &Vl[buf][j * 512 + lane * 8]);
    }
  };

  stage(0, 0);
  __syncthreads();          // drains vmcnt(0): tile 0 landed
  int cur = 0;

  // bpermute addressing for the P redistribution (derived & element-checked):
  // target lane (l15,quad), chunk c, reg g needs pk[2c + (quad>=2)][g&1]
  // from lane l15 + 16*((quad&1)*2 + (g>>1)).
  const int addrA = (l15 + (quad & 1) * 32) * 4;   // for g = 0,1
  const int addrB = addrA + 64;                    // for g = 2,3 (+16 lanes)
  const bool hb = (quad >= 2);

  for (int kb = 0; kb <= qb; ++kb) {
    if (kb < qb) stage(cur ^ 1, kb + 1);     // prefetch next tile; flies under compute
    const int k0 = kb * 64;
    const bool last = (kb == qb);
    const int nsub   = last ? (wave + 1) : 4;        // QK^T subtiles needed
    const int nchunk = last ? ((wave >> 1) + 1) : 2; // PV 32-key chunks needed

    // QK^T swapped: s[sub][r] = P[q = q0+l15][k = k0 + sub*16 + quad*4 + r]
    f32x4 s[4];
#pragma unroll
    for (int sub = 0; sub < 4; ++sub) {
      if (sub < nsub) {
        const u16* kr = &Kl[cur][(sub * 16 + l15) * 104 + quad * 8];
        const s16x8 b0 = *(const s16x8*)(kr);
        const s16x8 b1 = *(const s16x8*)(kr + 32);
        const s16x8 b2 = *(const s16x8*)(kr + 64);
        f32x4 t = __builtin_amdgcn_mfma_f32_16x16x32_bf16(b0, aq[0], zero4, 0, 0, 0);
        t = __builtin_amdgcn_mfma_f32_16x16x32_bf16(b1, aq[1], t, 0, 0, 0);
        t = __builtin_amdgcn_mfma_f32_16x16x32_bf16(b2, aq[2], t, 0, 0, 0);
        s[sub] = t;
      } else {
        s[sub] = (f32x4){-1e30f, -1e30f, -1e30f, -1e30f};
      }
    }

    // causal mask only ever bites in the diagonal block
    if (last) {
      const int q = q0 + l15;
#pragma unroll
      for (int sub = 0; sub < 4; ++sub)
#pragma unroll
        for (int r = 0; r < 4; ++r) {
          const int k = k0 + sub * 16 + quad * 4 + r;
          if (k > q) s[sub][r] = -1e30f;
        }
    }

    // online softmax — in-register row reduce + 2 shfl_xor across the 4 quads
    float mx = s[0][0];
#pragma unroll
    for (int sub = 0; sub < 4; ++sub)
#pragma unroll
      for (int r = 0; r < 4; ++r) mx = fmaxf(mx, s[sub][r]);
    mx = fmaxf(mx, __shfl_xor(mx, 16));
    mx = fmaxf(mx, __shfl_xor(mx, 32));
    const float mn = fmaxf(m_, mx);
    const float al = __expf(m_ - mn);
    m_ = mn;
#pragma unroll
    for (int sub = 0; sub < 4; ++sub)
#pragma unroll
      for (int r = 0; r < 4; ++r) s[sub][r] = __expf(s[sub][r] - mn);
    float rs = (((s[0][0] + s[0][1]) + (s[0][2] + s[0][3])) +
                ((s[1][0] + s[1][1]) + (s[1][2] + s[1][3]))) +
               (((s[2][0] + s[2][1]) + (s[2][2] + s[2][3])) +
                ((s[3][0] + s[3][1]) + (s[3][2] + s[3][3])));
    rs += __shfl_xor(rs, 16);
    rs += __shfl_xor(rs, 32);
    l_ = l_ * al + rs;

    // redistribute alpha to the o accumulator layout (q = quad*4 + r lives in lane quad*4+r)
    float alr[4];
#pragma unroll
    for (int r = 0; r < 4; ++r)
      alr[r] = __int_as_float(__builtin_amdgcn_ds_bpermute((quad * 4 + r) * 4,
                                                           __float_as_int(al)));
#pragma unroll
    for (int d = 0; d < 6; ++d)
#pragma unroll
      for (int r = 0; r < 4; ++r) o[d][r] *= alr[r];

    // pack P pairs to bf16x2: pk[sub][t] = (bf16(s[sub][2t]), bf16(s[sub][2t+1]))
    unsigned pk[4][2];
#pragma unroll
    for (int sub = 0; sub < 4; ++sub) {
      asm("v_cvt_pk_bf16_f32 %0, %1, %2" : "=v"(pk[sub][0]) : "v"(s[sub][0]), "v"(s[sub][1]));
      asm("v_cvt_pk_bf16_f32 %0, %1, %2" : "=v"(pk[sub][1]) : "v"(s[sub][2]), "v"(s[sub][3]));
    }

    // PV: A-fragment assembled in-register via ds_bpermute; B-fragment from staged V
#pragma unroll
    for (int c = 0; c < 2; ++c) {
      if (c < nchunk) {
        const int a00 = __builtin_amdgcn_ds_bpermute(addrA, (int)pk[c * 2][0]);
        const int a01 = __builtin_amdgcn_ds_bpermute(addrA, (int)pk[c * 2][1]);
        const int a10 = __builtin_amdgcn_ds_bpermute(addrA, (int)pk[c * 2 + 1][0]);
        const int a11 = __builtin_amdgcn_ds_bpermute(addrA, (int)pk[c * 2 + 1][1]);
        const int b00 = __builtin_amdgcn_ds_bpermute(addrB, (int)pk[c * 2][0]);
        const int b01 = __builtin_amdgcn_ds_bpermute(addrB, (int)pk[c * 2][1]);
        const int b10 = __builtin_amdgcn_ds_bpermute(addrB, (int)pk[c * 2 + 1][0]);
        const int b11 = __builtin_amdgcn_ds_bpermute(addrB, (int)pk[c * 2 + 1][1]);
        union { s16x8 v; int u[4]; } ap;
        ap.u[0] = hb ? a10 : a00;
        ap.u[1] = hb ? a11 : a01;
        ap.u[2] = hb ? b10 : b00;
        ap.u[3] = hb ? b11 : b01;
#pragma unroll
        for (int dblk = 0; dblk < 6; ++dblk) {
          const int d = dblk * 16 + l15;
          const s16x8 bv = *(const s16x8*)(&Vl[cur][d * 64 + (((c * 4 + quad) ^ (d & 7)) * 8)]);
          o[dblk] = __builtin_amdgcn_mfma_f32_16x16x32_bf16(ap.v, bv, o[dblk], 0, 0, 0);
        }
      }
    }

    __syncthreads();   // implicit vmcnt(0)+lgkmcnt(0) drain: next tile landed, cur free
    cur ^= 1;
  }

  // write ctx[b, q, h*96 + d] bf16 (o layout: row q = quad*4+r, col d = dblk*16+l15)
  const int b = bh >> 5, h = bh & 31;
  float invl[4];
#pragma unroll
  for (int r = 0; r < 4; ++r) {
    const int v = __builtin_amdgcn_ds_bpermute((quad * 4 + r) * 4, __float_as_int(l_));
    invl[r] = 1.0f / __int_as_float(v);
  }
#pragma unroll
  for (int d = 0; d < 6; ++d)
#pragma unroll
    for (int r = 0; r < 4; ++r) {
      const int row = q0 + quad * 4 + r;
      ctx[((size_t)(b * 2048 + row)) * 3072 + h * 96 + d * 16 + l15] = f2bf(o[d][r] * invl[r]);
    }
}

// ---------------- launch ----------------
extern "C" void kernel_launch(void* const* d_in, const int* in_sizes, int n_in,
                              void* d_out, int out_size, void* d_ws, size_t ws_size,
                              hipStream_t stream) {
  const float* x    = (const float*)d_in[0];   // [2,2048,3072]
  const float* Wqkv = (const float*)d_in[1];   // [9216,3072]
  const float* Wo   = (const float*)d_in[2];   // [3072,3072]
  float* out = (float*)d_out;                  // [2,2048,3072] fp32

  char* ws = (char*)d_ws;
  u16* wq_b  = (u16*)(ws);                  // 56,623,104 B
  u16* wo_b  = (u16*)(ws + 56623104);       // 18,874,368 B
  u16* x_b   = (u16*)(ws + 75497472);       // 25,165,824 B
  u16* qkv_b = (u16*)(ws + 100663296);      // 75,497,472 B
  u16* K_b   = (u16*)(ws + 176160768);      // 25,165,824 B
  u16* Vt_b  = (u16*)(ws + 201326592);      // 25,165,824 B
  u16* Q_b   = x_b;                         // alias: x dead after GEMM1
  u16* ctx_b = qkv_b;                       // alias: qkv dead after rope_split

  cvt_f32_bf16<<<27648, 256, 0, stream>>>(Wqkv, wq_b, 28311552 / 4);
  cvt_f32_bf16<<<9216,  256, 0, stream>>>(Wo,   wo_b,  9437184 / 4);
  cvt_f32_bf16<<<12288, 256, 0, stream>>>(x,    x_b,  12582912 / 4);

  // qkv = x @ Wqkv^T   [4096 x 9216], K=3072  (16x36 = 576 tiles)
  gemm_nt256<true><<<576, 512, 0, stream>>>(x_b, wq_b, (void*)qkv_b, 4096, 9216, 3072);

  rope_split<<<4096, 256, 0, stream>>>(qkv_b, Q_b, K_b, Vt_b);

  attn<<<dim3(32, 64), 256, 0, stream>>>(Q_b, K_b, Vt_b, ctx_b);

  // out = ctx @ Wo^T   [4096 x 3072], K=3072, fp32 out  (16x12 = 192 tiles)
  gemm_nt256<false><<<192, 512, 0, stream>>>(ctx_b, wo_b, (void*)out, 4096, 3072, 3072);
}

// Round 5
// 834.714 us; speedup vs baseline: 1.4341x; 1.0522x over previous
//
#include <hip/hip_runtime.h>
#include <cstdint>

typedef short s16x8 __attribute__((ext_vector_type(8)));
typedef float f32x4 __attribute__((ext_vector_type(4)));
typedef unsigned short u16;

#define DEV static __device__ __forceinline__

DEV float bf2f(u16 b) {
  union { unsigned u; float f; } v; v.u = ((unsigned)b) << 16; return v.f;
}
DEV u16 f2bf(float f) {
  union { float f; unsigned u; } v; v.f = f;
  unsigned r = 0x7fffu + ((v.u >> 16) & 1u);   // RNE
  return (u16)((v.u + r) >> 16);
}

typedef __attribute__((address_space(3))) void lds_void_t;
typedef const __attribute__((address_space(1))) void glob_void_t;

DEV void async_copy16(const void* g, void* l) {
  __builtin_amdgcn_global_load_lds(
      (glob_void_t*)(uintptr_t)g,
      (lds_void_t*)(uint32_t)(uintptr_t)l,
      16, 0, 0);
}

// ---------------- fp32 -> bf16 convert (vectorized x4) ----------------
__global__ void cvt_f32_bf16(const float* __restrict__ in, u16* __restrict__ out, int n4) {
  int i = blockIdx.x * 256 + threadIdx.x;
  if (i < n4) {
    const float4 v = reinterpret_cast<const float4*>(in)[i];
    ushort4 o;
    o.x = f2bf(v.x); o.y = f2bf(v.y); o.z = f2bf(v.z); o.w = f2bf(v.w);
    reinterpret_cast<ushort4*>(out)[i] = o;
  }
}

// ---------------- 256xBN NT GEMM, phase-split schedule ----------------
// C[m,n] = sum_k A[m,k]*B[n,k]; A,B row-major bf16 K-contiguous.
// BM=256, BN=NI*64, BK=64, 512 thr = 8 waves (2M x 4N), per-wave 128 x NI*16,
// acc[8][NI]. LDS double-buffered. Per K-tile: 4+NI global_load_lds issues/thread
// (next tile) BEFORE ds_reads, then 4 phases {ds_read_b128 -> s_barrier ->
// setprio(1) -> 4*NI MFMA -> setprio(0)}; one __syncthreads per tile.
// LDS swizzle: chunk ^= row&7 (16B granularity), applied on the GLOBAL SOURCE
// during staging (LDS dest stays lane-linear) and on the ds_read address.
// Grid: 1-D, bijective XCD swizzle (nwg divisible by 8 for our shapes 768/256).
// NI=3 (BN=192) chosen so QKV grid = 768 = 3.00x256 CUs and o_proj = 256 = 1.00x
// (was 576 = 2.25 rounds -> 25% idle tail at 1 block/CU).
template <int NI, bool OUT_BF16>
__global__ __launch_bounds__(512, 2)
void gemm_nt256(const u16* __restrict__ A, const u16* __restrict__ B,
                void* __restrict__ C, int M, int N, int K) {
  __shared__ alignas(16) u16 As[2][256 * 64];        // 2 x 32 KB
  __shared__ alignas(16) u16 Bs[2][NI * 64 * 64];    // 2 x NI*8 KB
  const int tid  = threadIdx.x;
  const int lane = tid & 63;
  const int wave = tid >> 6;
  const int wm = wave >> 2, wn = wave & 3;
  const int l15 = lane & 15, quad = lane >> 4;
  const int BN = NI * 64;

  // XCD-aware swizzle: consecutive swz share a B-panel within an XCD's L2
  const int nwg = gridDim.x;
  const int cpx = nwg >> 3;                       // nwg % 8 == 0 for our shapes
  const int swz = (blockIdx.x & 7) * cpx + (blockIdx.x >> 3);
  const int mb  = M >> 8;
  const int bm  = swz % mb, bn = swz / mb;

  f32x4 acc[8][NI];
  const f32x4 zero4 = {0.f, 0.f, 0.f, 0.f};
#pragma unroll
  for (int mi = 0; mi < 8; ++mi)
#pragma unroll
    for (int ni = 0; ni < NI; ++ni) acc[mi][ni] = zero4;

  const size_t Abase = (size_t)(bm * 256) * K;
  const size_t Bbase = (size_t)bn * BN * K;

  // Stage one 256x64 A-tile + BNx64 B-tile into LDS buffer `buf`.
  auto stage = [&](int buf, int kt) {
#pragma unroll
    for (int j = 0; j < 4; ++j) {
      const int id  = j * 512 + tid;        // 0..2047 = 256 rows x 8 chunks
      const int row = id >> 3;
      const int sc  = ((id & 7) ^ (row & 7)) * 8;
      async_copy16(A + Abase + (size_t)row * K + kt + sc, &As[buf][id * 8]);
    }
#pragma unroll
    for (int j = 0; j < NI; ++j) {
      const int id  = j * 512 + tid;        // 0..NI*512-1 = BN rows x 8 chunks
      const int row = id >> 3;
      const int sc  = ((id & 7) ^ (row & 7)) * 8;
      async_copy16(B + Bbase + (size_t)row * K + kt + sc, &Bs[buf][id * 8]);
    }
  };

  stage(0, 0);
  __syncthreads();            // drains vmcnt(0): tile 0 landed
  int cur = 0;
  const int NT = K >> 6;

  for (int t = 0; t < NT; ++t) {
    if (t + 1 < NT) stage(cur ^ 1, (t + 1) << 6);   // prefetch; flies under 4 phases

    // B-frags for the whole tile (2*NI x ds_read_b128), reused by all 4 phases
    s16x8 bfr[2][NI];
#pragma unroll
    for (int ks = 0; ks < 2; ++ks)
#pragma unroll
      for (int ni = 0; ni < NI; ++ni) {
        const int row = wn * (NI * 16) + ni * 16 + l15;
        bfr[ks][ni] = *(const s16x8*)(&Bs[cur][row * 64 + ((ks * 4 + quad) ^ (row & 7)) * 8]);
      }

#pragma unroll
    for (int qd = 0; qd < 4; ++qd) {
      s16x8 afr[2][2];
#pragma unroll
      for (int ks = 0; ks < 2; ++ks)
#pragma unroll
        for (int mm = 0; mm < 2; ++mm) {
          const int row = wm * 128 + (qd * 2 + mm) * 16 + l15;
          afr[ks][mm] = *(const s16x8*)(&As[cur][row * 64 + ((ks * 4 + quad) ^ (row & 7)) * 8]);
        }
      __builtin_amdgcn_s_barrier();
      __builtin_amdgcn_sched_barrier(0);
      __builtin_amdgcn_s_setprio(1);
#pragma unroll
      for (int ks = 0; ks < 2; ++ks)
#pragma unroll
        for (int mm = 0; mm < 2; ++mm)
#pragma unroll
          for (int ni = 0; ni < NI; ++ni)
            acc[qd * 2 + mm][ni] = __builtin_amdgcn_mfma_f32_16x16x32_bf16(
                afr[ks][mm], bfr[ks][ni], acc[qd * 2 + mm][ni], 0, 0, 0);
      __builtin_amdgcn_s_setprio(0);
    }
    __syncthreads();          // vmcnt(0)+lgkmcnt(0) drain: next tile landed, cur free
    cur ^= 1;
  }

#pragma unroll
  for (int mi = 0; mi < 8; ++mi) {
#pragma unroll
    for (int ni = 0; ni < NI; ++ni) {
      const int gm0 = bm * 256 + wm * 128 + mi * 16 + quad * 4;
      const int gn  = bn * BN + wn * (NI * 16) + ni * 16 + l15;
#pragma unroll
      for (int r = 0; r < 4; ++r) {
        const size_t idx = (size_t)(gm0 + r) * N + gn;
        if (OUT_BF16) ((u16*)C)[idx] = f2bf(acc[mi][ni][r]);
        else          ((float*)C)[idx] = acc[mi][ni][r];
      }
    }
  }
}

// ---------------- RoPE + split + layout change (vectorized x4) ----------------
__global__ void rope_split(const u16* __restrict__ qkv, u16* __restrict__ Q,
                           u16* __restrict__ Kb, u16* __restrict__ Vt) {
  const int tok = blockIdx.x;          // 0..4095
  const int b = tok >> 11, l = tok & 2047;
  const float pos = (float)l;
  const float SF = 1.1902380714238083f;          // sqrt(1 + log(32)/log(4096))
  const float QSCALE = 0.10206207261596575f;     // 96^-0.5
  const size_t base = (size_t)tok * 9216;
  for (int i = threadIdx.x; i < 768; i += 256) {
    const int g = i * 4;
    const int h = g / 96, d0 = g - h * 96;       // d0 multiple of 4; halves aligned
    const ushort4 qv4 = *(const ushort4*)(qkv + base + g);
    const ushort4 kv4 = *(const ushort4*)(qkv + base + 3072 + g);
    const ushort4 vv4 = *(const ushort4*)(qkv + base + 6144 + g);
    const int dp0    = (d0 < 48) ? d0 + 48 : d0 - 48;
    const float sgn  = (d0 < 48) ? -1.0f : 1.0f;
    const ushort4 qp4 = *(const ushort4*)(qkv + base + h * 96 + dp0);
    const ushort4 kp4 = *(const ushort4*)(qkv + base + 3072 + h * 96 + dp0);
    const int fi0 = (d0 < 48) ? d0 : d0 - 48;
    const int bh = b * 32 + h;
    ushort4 qo, ko;
    const u16* qvp = (const u16*)&qv4; const u16* kvp = (const u16*)&kv4;
    const u16* qpp = (const u16*)&qp4; const u16* kpp = (const u16*)&kp4;
    const u16* vvp = (const u16*)&vv4;
    u16* qop = (u16*)&qo; u16* kop = (u16*)&ko;
#pragma unroll
    for (int e = 0; e < 4; ++e) {
      const float inv = exp2f(-13.287712379549449f * ((float)(fi0 + e) * (1.0f / 48.0f)));
      const float ang = pos * inv;
      float s, c;
      sincosf(ang, &s, &c);
      c *= SF; s *= SF;
      const float qout = bf2f(qvp[e]) * c + bf2f(qpp[e]) * sgn * s;
      const float kout = bf2f(kvp[e]) * c + bf2f(kpp[e]) * sgn * s;
      qop[e] = f2bf(qout * QSCALE);
      kop[e] = f2bf(kout);
      Vt[((size_t)bh * 96 + d0 + e) * 2048 + l] = vvp[e];
    }
    *(ushort4*)(Q  + ((size_t)bh * 2048 + l) * 96 + d0) = qo;
    *(ushort4*)(Kb + ((size_t)bh * 2048 + l) * 96 + d0) = ko;
  }
}

// ---------------- flash attention (causal), LDS-staged K/V, swapped-QK^T softmax ----------------
// (unchanged from R3/R4 — isolating the GEMM shape change this round)
__global__ __launch_bounds__(256, 3)
void attn(const u16* __restrict__ Q, const u16* __restrict__ Kb,
          const u16* __restrict__ Vt, u16* __restrict__ ctx) {
  const int qb = 31 - blockIdx.x;   // heavy blocks first
  const int bh = blockIdx.y;        // 0..63
  const int tid = threadIdx.x, lane = tid & 63, wave = tid >> 6;
  const int l15 = lane & 15, quad = lane >> 4;

  __shared__ alignas(16) u16 Kl[2][64 * 104];   // 2 x 13312 B
  __shared__ alignas(16) u16 Vl[2][96 * 64];    // 2 x 12288 B

  const size_t hbase = (size_t)bh * 2048 * 96;
  const int q0 = qb * 64 + wave * 16;

  s16x8 aq[3];
#pragma unroll
  for (int c = 0; c < 3; ++c)
    aq[c] = *(const s16x8*)(Q + hbase + (size_t)(q0 + l15) * 96 + c * 32 + quad * 8);

  float m_ = -1e30f, l_ = 0.f;        // per-lane: q-row q0+l15 (replicated across quads)
  f32x4 o[6];
  const f32x4 zero4 = {0.f, 0.f, 0.f, 0.f};
#pragma unroll
  for (int d = 0; d < 6; ++d) o[d] = zero4;

  // Stage one 64-key K/V tile into LDS buffer `buf` (all 4 waves cooperate).
  auto stage = [&](int buf, int kb) {
    const int k0 = kb * 64;
    // K: 64 rows x 13 chunks of 16B (last chunk = pad, sourced from a safe in-row addr)
    for (int j = wave; j < 13; j += 4) {
      const int id = j * 64 + lane;          // 0..831
      const int k  = id / 13;
      const int cc = id - k * 13;
      const u16* src = Kb + hbase + (size_t)(k0 + k) * 96 + (cc < 12 ? cc * 8 : 0);
      async_copy16(src, &Kl[buf][j * 512 + lane * 8]);
    }
    // V: 96 rows x 8 chunks of 16B, XOR-swizzled source
    for (int j = wave; j < 12; j += 4) {
      const int id = j * 64 + lane;          // 0..767
      const int d  = id >> 3;
      const int lc = (id & 7) ^ (d & 7);
      const u16* src = Vt + ((size_t)bh * 96 + d) * 2048 + k0 + lc * 8;
      async_copy16(src, &Vl[buf][j * 512 + lane * 8]);
    }
  };

  stage(0, 0);
  __syncthreads();          // drains vmcnt(0): tile 0 landed
  int cur = 0;

  // bpermute addressing for the P redistribution (derived & element-checked):
  // target lane (l15,quad), chunk c, reg g needs pk[2c + (quad>=2)][g&1]
  // from lane l15 + 16*((quad&1)*2 + (g>>1)).
  const int addrA = (l15 + (quad & 1) * 32) * 4;   // for g = 0,1
  const int addrB = addrA + 64;                    // for g = 2,3 (+16 lanes)
  const bool hb = (quad >= 2);

  for (int kb = 0; kb <= qb; ++kb) {
    if (kb < qb) stage(cur ^ 1, kb + 1);     // prefetch next tile; flies under compute
    const int k0 = kb * 64;
    const bool last = (kb == qb);
    const int nsub   = last ? (wave + 1) : 4;        // QK^T subtiles needed
    const int nchunk = last ? ((wave >> 1) + 1) : 2; // PV 32-key chunks needed

    // QK^T swapped: s[sub][r] = P[q = q0+l15][k = k0 + sub*16 + quad*4 + r]
    f32x4 s[4];
#pragma unroll
    for (int sub = 0; sub < 4; ++sub) {
      if (sub < nsub) {
        const u16* kr = &Kl[cur][(sub * 16 + l15) * 104 + quad * 8];
        const s16x8 b0 = *(const s16x8*)(kr);
        const s16x8 b1 = *(const s16x8*)(kr + 32);
        const s16x8 b2 = *(const s16x8*)(kr + 64);
        f32x4 t = __builtin_amdgcn_mfma_f32_16x16x32_bf16(b0, aq[0], zero4, 0, 0, 0);
        t = __builtin_amdgcn_mfma_f32_16x16x32_bf16(b1, aq[1], t, 0, 0, 0);
        t = __builtin_amdgcn_mfma_f32_16x16x32_bf16(b2, aq[2], t, 0, 0, 0);
        s[sub] = t;
      } else {
        s[sub] = (f32x4){-1e30f, -1e30f, -1e30f, -1e30f};
      }
    }

    // causal mask only ever bites in the diagonal block
    if (last) {
      const int q = q0 + l15;
#pragma unroll
      for (int sub = 0; sub < 4; ++sub)
#pragma unroll
        for (int r = 0; r < 4; ++r) {
          const int k = k0 + sub * 16 + quad * 4 + r;
          if (k > q) s[sub][r] = -1e30f;
        }
    }

    // online softmax — in-register row reduce + 2 shfl_xor across the 4 quads
    float mx = s[0][0];
#pragma unroll
    for (int sub = 0; sub < 4; ++sub)
#pragma unroll
      for (int r = 0; r < 4; ++r) mx = fmaxf(mx, s[sub][r]);
    mx = fmaxf(mx, __shfl_xor(mx, 16));
    mx = fmaxf(mx, __shfl_xor(mx, 32));
    const float mn = fmaxf(m_, mx);
    const float al = __expf(m_ - mn);
    m_ = mn;
#pragma unroll
    for (int sub = 0; sub < 4; ++sub)
#pragma unroll
      for (int r = 0; r < 4; ++r) s[sub][r] = __expf(s[sub][r] - mn);
    float rs = (((s[0][0] + s[0][1]) + (s[0][2] + s[0][3])) +
                ((s[1][0] + s[1][1]) + (s[1][2] + s[1][3]))) +
               (((s[2][0] + s[2][1]) + (s[2][2] + s[2][3])) +
                ((s[3][0] + s[3][1]) + (s[3][2] + s[3][3])));
    rs += __shfl_xor(rs, 16);
    rs += __shfl_xor(rs, 32);
    l_ = l_ * al + rs;

    // redistribute alpha to the o accumulator layout (q = quad*4 + r lives in lane quad*4+r)
    float alr[4];
#pragma unroll
    for (int r = 0; r < 4; ++r)
      alr[r] = __int_as_float(__builtin_amdgcn_ds_bpermute((quad * 4 + r) * 4,
                                                           __float_as_int(al)));
#pragma unroll
    for (int d = 0; d < 6; ++d)
#pragma unroll
      for (int r = 0; r < 4; ++r) o[d][r] *= alr[r];

    // pack P pairs to bf16x2: pk[sub][t] = (bf16(s[sub][2t]), bf16(s[sub][2t+1]))
    unsigned pk[4][2];
#pragma unroll
    for (int sub = 0; sub < 4; ++sub) {
      asm("v_cvt_pk_bf16_f32 %0, %1, %2" : "=v"(pk[sub][0]) : "v"(s[sub][0]), "v"(s[sub][1]));
      asm("v_cvt_pk_bf16_f32 %0, %1, %2" : "=v"(pk[sub][1]) : "v"(s[sub][2]), "v"(s[sub][3]));
    }

    // PV: A-fragment assembled in-register via ds_bpermute; B-fragment from staged V
#pragma unroll
    for (int c = 0; c < 2; ++c) {
      if (c < nchunk) {
        const int a00 = __builtin_amdgcn_ds_bpermute(addrA, (int)pk[c * 2][0]);
        const int a01 = __builtin_amdgcn_ds_bpermute(addrA, (int)pk[c * 2][1]);
        const int a10 = __builtin_amdgcn_ds_bpermute(addrA, (int)pk[c * 2 + 1][0]);
        const int a11 = __builtin_amdgcn_ds_bpermute(addrA, (int)pk[c * 2 + 1][1]);
        const int b00 = __builtin_amdgcn_ds_bpermute(addrB, (int)pk[c * 2][0]);
        const int b01 = __builtin_amdgcn_ds_bpermute(addrB, (int)pk[c * 2][1]);
        const int b10 = __builtin_amdgcn_ds_bpermute(addrB, (int)pk[c * 2 + 1][0]);
        const int b11 = __builtin_amdgcn_ds_bpermute(addrB, (int)pk[c * 2 + 1][1]);
        union { s16x8 v; int u[4]; } ap;
        ap.u[0] = hb ? a10 : a00;
        ap.u[1] = hb ? a11 : a01;
        ap.u[2] = hb ? b10 : b00;
        ap.u[3] = hb ? b11 : b01;
#pragma unroll
        for (int dblk = 0; dblk < 6; ++dblk) {
          const int d = dblk * 16 + l15;
          const s16x8 bv = *(const s16x8*)(&Vl[cur][d * 64 + (((c * 4 + quad) ^ (d & 7)) * 8)]);
          o[dblk] = __builtin_amdgcn_mfma_f32_16x16x32_bf16(ap.v, bv, o[dblk], 0, 0, 0);
        }
      }
    }

    __syncthreads();   // implicit vmcnt(0)+lgkmcnt(0) drain: next tile landed, cur free
    cur ^= 1;
  }

  // write ctx[b, q, h*96 + d] bf16 (o layout: row q = quad*4+r, col d = dblk*16+l15)
  const int b = bh >> 5, h = bh & 31;
  float invl[4];
#pragma unroll
  for (int r = 0; r < 4; ++r) {
    const int v = __builtin_amdgcn_ds_bpermute((quad * 4 + r) * 4, __float_as_int(l_));
    invl[r] = 1.0f / __int_as_float(v);
  }
#pragma unroll
  for (int d = 0; d < 6; ++d)
#pragma unroll
    for (int r = 0; r < 4; ++r) {
      const int row = q0 + quad * 4 + r;
      ctx[((size_t)(b * 2048 + row)) * 3072 + h * 96 + d * 16 + l15] = f2bf(o[d][r] * invl[r]);
    }
}

// ---------------- launch ----------------
extern "C" void kernel_launch(void* const* d_in, const int* in_sizes, int n_in,
                              void* d_out, int out_size, void* d_ws, size_t ws_size,
                              hipStream_t stream) {
  const float* x    = (const float*)d_in[0];   // [2,2048,3072]
  const float* Wqkv = (const float*)d_in[1];   // [9216,3072]
  const float* Wo   = (const float*)d_in[2];   // [3072,3072]
  float* out = (float*)d_out;                  // [2,2048,3072] fp32

  char* ws = (char*)d_ws;
  u16* wq_b  = (u16*)(ws);                  // 56,623,104 B
  u16* wo_b  = (u16*)(ws + 56623104);       // 18,874,368 B
  u16* x_b   = (u16*)(ws + 75497472);       // 25,165,824 B
  u16* qkv_b = (u16*)(ws + 100663296);      // 75,497,472 B
  u16* K_b   = (u16*)(ws + 176160768);      // 25,165,824 B
  u16* Vt_b  = (u16*)(ws + 201326592);      // 25,165,824 B
  u16* Q_b   = x_b;                         // alias: x dead after GEMM1
  u16* ctx_b = qkv_b;                       // alias: qkv dead after rope_split

  cvt_f32_bf16<<<27648, 256, 0, stream>>>(Wqkv, wq_b, 28311552 / 4);
  cvt_f32_bf16<<<9216,  256, 0, stream>>>(Wo,   wo_b,  9437184 / 4);
  cvt_f32_bf16<<<12288, 256, 0, stream>>>(x,    x_b,  12582912 / 4);

  // qkv = x @ Wqkv^T   [4096 x 9216], K=3072  (16 x 48 = 768 tiles = 3.00 rounds)
  gemm_nt256<3, true><<<768, 512, 0, stream>>>(x_b, wq_b, (void*)qkv_b, 4096, 9216, 3072);

  rope_split<<<4096, 256, 0, stream>>>(qkv_b, Q_b, K_b, Vt_b);

  attn<<<dim3(32, 64), 256, 0, stream>>>(Q_b, K_b, Vt_b, ctx_b);

  // out = ctx @ Wo^T   [4096 x 3072], K=3072, fp32 out  (16 x 16 = 256 tiles = 1.00 round)
  gemm_nt256<3, false><<<256, 512, 0, stream>>>(ctx_b, wo_b, (void*)out, 4096, 3072, 3072);
}

// Round 6
// 828.662 us; speedup vs baseline: 1.4445x; 1.0073x over previous
//
#include <hip/hip_runtime.h>
#include <cstdint>

typedef short s16x8 __attribute__((ext_vector_type(8)));
typedef float f32x4 __attribute__((ext_vector_type(4)));
typedef unsigned short u16;

#define DEV static __device__ __forceinline__

DEV float bf2f(u16 b) {
  union { unsigned u; float f; } v; v.u = ((unsigned)b) << 16; return v.f;
}
DEV u16 f2bf(float f) {
  union { float f; unsigned u; } v; v.f = f;
  unsigned r = 0x7fffu + ((v.u >> 16) & 1u);   // RNE
  return (u16)((v.u + r) >> 16);
}

typedef __attribute__((address_space(3))) void lds_void_t;
typedef const __attribute__((address_space(1))) void glob_void_t;

DEV void async_copy16(const void* g, void* l) {
  __builtin_amdgcn_global_load_lds(
      (glob_void_t*)(uintptr_t)g,
      (lds_void_t*)(uint32_t)(uintptr_t)l,
      16, 0, 0);
}

// ---------------- fp32 -> bf16 convert (vectorized x4) ----------------
__global__ void cvt_f32_bf16(const float* __restrict__ in, u16* __restrict__ out, int n4) {
  int i = blockIdx.x * 256 + threadIdx.x;
  if (i < n4) {
    const float4 v = reinterpret_cast<const float4*>(in)[i];
    ushort4 o;
    o.x = f2bf(v.x); o.y = f2bf(v.y); o.z = f2bf(v.z); o.w = f2bf(v.w);
    reinterpret_cast<ushort4*>(out)[i] = o;
  }
}

// ---------------- 256xBN NT GEMM, barrier-free intra-tile pipeline ----------------
// C[m,n] = sum_k A[m,k]*B[n,k]; A,B row-major bf16 K-contiguous.
// BM=256, BN=NI*64, BK=64, 512 thr = 8 waves (2M x 4N), per-wave 128 x NI*16,
// acc[8][NI]. LDS double-buffered. Per K-tile: stage next tile (4+NI issues/thr)
// FIRST, then bfr (2*NI ds_read) + a software-pipelined quadrant loop:
// {read afr[qd+1] -> setprio(1) -> 12 MFMA on afr[qd] -> setprio(0)} with NO
// intra-tile barriers (reads come from the buffer sealed by last tile's
// __syncthreads; removing the per-phase barrier lets waves drift so one wave's
// ds_reads overlap another's MFMAs, and afr[qd+1] latency hides under qd's MFMAs).
// One __syncthreads per tile (vmcnt+lgkm drain = staging handshake).
// LDS swizzle: chunk ^= row&7 (16B), applied on the GLOBAL SOURCE during staging
// (LDS dest stays lane-linear) and on the ds_read address.
// Grid: 1-D, bijective XCD swizzle (nwg divisible by 8 for our shapes 768/256).
// NI=3 (BN=192): QKV grid = 768 = 3.00x256 CUs, o_proj = 256 = 1.00x.
template <int NI, bool OUT_BF16>
__global__ __launch_bounds__(512, 2)
void gemm_nt256(const u16* __restrict__ A, const u16* __restrict__ B,
                void* __restrict__ C, int M, int N, int K) {
  __shared__ alignas(16) u16 As[2][256 * 64];        // 2 x 32 KB
  __shared__ alignas(16) u16 Bs[2][NI * 64 * 64];    // 2 x NI*8 KB
  const int tid  = threadIdx.x;
  const int lane = tid & 63;
  const int wave = tid >> 6;
  const int wm = wave >> 2, wn = wave & 3;
  const int l15 = lane & 15, quad = lane >> 4;
  const int BN = NI * 64;

  // XCD-aware swizzle: consecutive swz share a B-panel within an XCD's L2
  const int nwg = gridDim.x;
  const int cpx = nwg >> 3;                       // nwg % 8 == 0 for our shapes
  const int swz = (blockIdx.x & 7) * cpx + (blockIdx.x >> 3);
  const int mb  = M >> 8;
  const int bm  = swz % mb, bn = swz / mb;

  f32x4 acc[8][NI];
  const f32x4 zero4 = {0.f, 0.f, 0.f, 0.f};
#pragma unroll
  for (int mi = 0; mi < 8; ++mi)
#pragma unroll
    for (int ni = 0; ni < NI; ++ni) acc[mi][ni] = zero4;

  const size_t Abase = (size_t)(bm * 256) * K;
  const size_t Bbase = (size_t)bn * BN * K;

  // Stage one 256x64 A-tile + BNx64 B-tile into LDS buffer `buf`.
  auto stage = [&](int buf, int kt) {
#pragma unroll
    for (int j = 0; j < 4; ++j) {
      const int id  = j * 512 + tid;        // 0..2047 = 256 rows x 8 chunks
      const int row = id >> 3;
      const int sc  = ((id & 7) ^ (row & 7)) * 8;
      async_copy16(A + Abase + (size_t)row * K + kt + sc, &As[buf][id * 8]);
    }
#pragma unroll
    for (int j = 0; j < NI; ++j) {
      const int id  = j * 512 + tid;        // 0..NI*512-1 = BN rows x 8 chunks
      const int row = id >> 3;
      const int sc  = ((id & 7) ^ (row & 7)) * 8;
      async_copy16(B + Bbase + (size_t)row * K + kt + sc, &Bs[buf][id * 8]);
    }
  };

  stage(0, 0);
  __syncthreads();            // drains vmcnt(0): tile 0 landed
  int cur = 0;
  const int NT = K >> 6;

  for (int t = 0; t < NT; ++t) {
    if (t + 1 < NT) stage(cur ^ 1, (t + 1) << 6);   // prefetch; flies under the tile

    // B-frags for the whole tile (2*NI x ds_read_b128), reused by all quadrants
    s16x8 bfr[2][NI];
#pragma unroll
    for (int ks = 0; ks < 2; ++ks)
#pragma unroll
      for (int ni = 0; ni < NI; ++ni) {
        const int row = wn * (NI * 16) + ni * 16 + l15;
        bfr[ks][ni] = *(const s16x8*)(&Bs[cur][row * 64 + ((ks * 4 + quad) ^ (row & 7)) * 8]);
      }

    // A-frag read for quadrant qd (4 x ds_read_b128), fully static dst
    auto lda = [&](s16x8 (&dst)[2][2], int qd) {
#pragma unroll
      for (int ks = 0; ks < 2; ++ks)
#pragma unroll
        for (int mm = 0; mm < 2; ++mm) {
          const int row = wm * 128 + (qd * 2 + mm) * 16 + l15;
          dst[ks][mm] = *(const s16x8*)(&As[cur][row * 64 + ((ks * 4 + quad) ^ (row & 7)) * 8]);
        }
    };
    // 12-MFMA cluster for quadrant qd
    auto mfmaq = [&](const s16x8 (&src)[2][2], int qd) {
      __builtin_amdgcn_s_setprio(1);
#pragma unroll
      for (int ks = 0; ks < 2; ++ks)
#pragma unroll
        for (int mm = 0; mm < 2; ++mm)
#pragma unroll
          for (int ni = 0; ni < NI; ++ni)
            acc[qd * 2 + mm][ni] = __builtin_amdgcn_mfma_f32_16x16x32_bf16(
                src[ks][mm], bfr[ks][ni], acc[qd * 2 + mm][ni], 0, 0, 0);
      __builtin_amdgcn_s_setprio(0);
    };

    // software pipeline: read qd+1's frags before qd's MFMA cluster
    s16x8 a0[2][2], a1[2][2];
    lda(a0, 0);
    lda(a1, 1); mfmaq(a0, 0);
    lda(a0, 2); mfmaq(a1, 1);
    lda(a1, 3); mfmaq(a0, 2);
    mfmaq(a1, 3);

    __syncthreads();          // vmcnt(0)+lgkmcnt(0) drain: next tile landed, cur free
    cur ^= 1;
  }

#pragma unroll
  for (int mi = 0; mi < 8; ++mi) {
#pragma unroll
    for (int ni = 0; ni < NI; ++ni) {
      const int gm0 = bm * 256 + wm * 128 + mi * 16 + quad * 4;
      const int gn  = bn * BN + wn * (NI * 16) + ni * 16 + l15;
#pragma unroll
      for (int r = 0; r < 4; ++r) {
        const size_t idx = (size_t)(gm0 + r) * N + gn;
        if (OUT_BF16) ((u16*)C)[idx] = f2bf(acc[mi][ni][r]);
        else          ((float*)C)[idx] = acc[mi][ni][r];
      }
    }
  }
}

// ---------------- RoPE + split + layout change (vectorized x4) ----------------
__global__ void rope_split(const u16* __restrict__ qkv, u16* __restrict__ Q,
                           u16* __restrict__ Kb, u16* __restrict__ Vt) {
  const int tok = blockIdx.x;          // 0..4095
  const int b = tok >> 11, l = tok & 2047;
  const float pos = (float)l;
  const float SF = 1.1902380714238083f;          // sqrt(1 + log(32)/log(4096))
  const float QSCALE = 0.10206207261596575f;     // 96^-0.5
  const size_t base = (size_t)tok * 9216;
  for (int i = threadIdx.x; i < 768; i += 256) {
    const int g = i * 4;
    const int h = g / 96, d0 = g - h * 96;       // d0 multiple of 4; halves aligned
    const ushort4 qv4 = *(const ushort4*)(qkv + base + g);
    const ushort4 kv4 = *(const ushort4*)(qkv + base + 3072 + g);
    const ushort4 vv4 = *(const ushort4*)(qkv + base + 6144 + g);
    const int dp0    = (d0 < 48) ? d0 + 48 : d0 - 48;
    const float sgn  = (d0 < 48) ? -1.0f : 1.0f;
    const ushort4 qp4 = *(const ushort4*)(qkv + base + h * 96 + dp0);
    const ushort4 kp4 = *(const ushort4*)(qkv + base + 3072 + h * 96 + dp0);
    const int fi0 = (d0 < 48) ? d0 : d0 - 48;
    const int bh = b * 32 + h;
    ushort4 qo, ko;
    const u16* qvp = (const u16*)&qv4; const u16* kvp = (const u16*)&kv4;
    const u16* qpp = (const u16*)&qp4; const u16* kpp = (const u16*)&kp4;
    const u16* vvp = (const u16*)&vv4;
    u16* qop = (u16*)&qo; u16* kop = (u16*)&ko;
#pragma unroll
    for (int e = 0; e < 4; ++e) {
      const float inv = exp2f(-13.287712379549449f * ((float)(fi0 + e) * (1.0f / 48.0f)));
      const float ang = pos * inv;
      float s, c;
      sincosf(ang, &s, &c);
      c *= SF; s *= SF;
      const float qout = bf2f(qvp[e]) * c + bf2f(qpp[e]) * sgn * s;
      const float kout = bf2f(kvp[e]) * c + bf2f(kpp[e]) * sgn * s;
      qop[e] = f2bf(qout * QSCALE);
      kop[e] = f2bf(kout);
      Vt[((size_t)bh * 96 + d0 + e) * 2048 + l] = vvp[e];
    }
    *(ushort4*)(Q  + ((size_t)bh * 2048 + l) * 96 + d0) = qo;
    *(ushort4*)(Kb + ((size_t)bh * 2048 + l) * 96 + d0) = ko;
  }
}

// ---------------- flash attention (causal), LDS-staged K/V, swapped-QK^T softmax ----------------
// (unchanged — isolating the GEMM schedule change this round)
__global__ __launch_bounds__(256, 3)
void attn(const u16* __restrict__ Q, const u16* __restrict__ Kb,
          const u16* __restrict__ Vt, u16* __restrict__ ctx) {
  const int qb = 31 - blockIdx.x;   // heavy blocks first
  const int bh = blockIdx.y;        // 0..63
  const int tid = threadIdx.x, lane = tid & 63, wave = tid >> 6;
  const int l15 = lane & 15, quad = lane >> 4;

  __shared__ alignas(16) u16 Kl[2][64 * 104];   // 2 x 13312 B
  __shared__ alignas(16) u16 Vl[2][96 * 64];    // 2 x 12288 B

  const size_t hbase = (size_t)bh * 2048 * 96;
  const int q0 = qb * 64 + wave * 16;

  s16x8 aq[3];
#pragma unroll
  for (int c = 0; c < 3; ++c)
    aq[c] = *(const s16x8*)(Q + hbase + (size_t)(q0 + l15) * 96 + c * 32 + quad * 8);

  float m_ = -1e30f, l_ = 0.f;        // per-lane: q-row q0+l15 (replicated across quads)
  f32x4 o[6];
  const f32x4 zero4 = {0.f, 0.f, 0.f, 0.f};
#pragma unroll
  for (int d = 0; d < 6; ++d) o[d] = zero4;

  // Stage one 64-key K/V tile into LDS buffer `buf` (all 4 waves cooperate).
  auto stage = [&](int buf, int kb) {
    const int k0 = kb * 64;
    // K: 64 rows x 13 chunks of 16B (last chunk = pad, sourced from a safe in-row addr)
    for (int j = wave; j < 13; j += 4) {
      const int id = j * 64 + lane;          // 0..831
      const int k  = id / 13;
      const int cc = id - k * 13;
      const u16* src = Kb + hbase + (size_t)(k0 + k) * 96 + (cc < 12 ? cc * 8 : 0);
      async_copy16(src, &Kl[buf][j * 512 + lane * 8]);
    }
    // V: 96 rows x 8 chunks of 16B, XOR-swizzled source
    for (int j = wave; j < 12; j += 4) {
      const int id = j * 64 + lane;          // 0..767
      const int d  = id >> 3;
      const int lc = (id & 7) ^ (d & 7);
      const u16* src = Vt + ((size_t)bh * 96 + d) * 2048 + k0 + lc * 8;
      async_copy16(src, &Vl[buf][j * 512 + lane * 8]);
    }
  };

  stage(0, 0);
  __syncthreads();          // drains vmcnt(0): tile 0 landed
  int cur = 0;

  // bpermute addressing for the P redistribution (derived & element-checked):
  // target lane (l15,quad), chunk c, reg g needs pk[2c + (quad>=2)][g&1]
  // from lane l15 + 16*((quad&1)*2 + (g>>1)).
  const int addrA = (l15 + (quad & 1) * 32) * 4;   // for g = 0,1
  const int addrB = addrA + 64;                    // for g = 2,3 (+16 lanes)
  const bool hb = (quad >= 2);

  for (int kb = 0; kb <= qb; ++kb) {
    if (kb < qb) stage(cur ^ 1, kb + 1);     // prefetch next tile; flies under compute
    const int k0 = kb * 64;
    const bool last = (kb == qb);
    const int nsub   = last ? (wave + 1) : 4;        // QK^T subtiles needed
    const int nchunk = last ? ((wave >> 1) + 1) : 2; // PV 32-key chunks needed

    // QK^T swapped: s[sub][r] = P[q = q0+l15][k = k0 + sub*16 + quad*4 + r]
    f32x4 s[4];
#pragma unroll
    for (int sub = 0; sub < 4; ++sub) {
      if (sub < nsub) {
        const u16* kr = &Kl[cur][(sub * 16 + l15) * 104 + quad * 8];
        const s16x8 b0 = *(const s16x8*)(kr);
        const s16x8 b1 = *(const s16x8*)(kr + 32);
        const s16x8 b2 = *(const s16x8*)(kr + 64);
        f32x4 t = __builtin_amdgcn_mfma_f32_16x16x32_bf16(b0, aq[0], zero4, 0, 0, 0);
        t = __builtin_amdgcn_mfma_f32_16x16x32_bf16(b1, aq[1], t, 0, 0, 0);
        t = __builtin_amdgcn_mfma_f32_16x16x32_bf16(b2, aq[2], t, 0, 0, 0);
        s[sub] = t;
      } else {
        s[sub] = (f32x4){-1e30f, -1e30f, -1e30f, -1e30f};
      }
    }

    // causal mask only ever bites in the diagonal block
    if (last) {
      const int q = q0 + l15;
#pragma unroll
      for (int sub = 0; sub < 4; ++sub)
#pragma unroll
        for (int r = 0; r < 4; ++r) {
          const int k = k0 + sub * 16 + quad * 4 + r;
          if (k > q) s[sub][r] = -1e30f;
        }
    }

    // online softmax — in-register row reduce + 2 shfl_xor across the 4 quads
    float mx = s[0][0];
#pragma unroll
    for (int sub = 0; sub < 4; ++sub)
#pragma unroll
      for (int r = 0; r < 4; ++r) mx = fmaxf(mx, s[sub][r]);
    mx = fmaxf(mx, __shfl_xor(mx, 16));
    mx = fmaxf(mx, __shfl_xor(mx, 32));
    const float mn = fmaxf(m_, mx);
    const float al = __expf(m_ - mn);
    m_ = mn;
#pragma unroll
    for (int sub = 0; sub < 4; ++sub)
#pragma unroll
      for (int r = 0; r < 4; ++r) s[sub][r] = __expf(s[sub][r] - mn);
    float rs = (((s[0][0] + s[0][1]) + (s[0][2] + s[0][3])) +
                ((s[1][0] + s[1][1]) + (s[1][2] + s[1][3]))) +
               (((s[2][0] + s[2][1]) + (s[2][2] + s[2][3])) +
                ((s[3][0] + s[3][1]) + (s[3][2] + s[3][3])));
    rs += __shfl_xor(rs, 16);
    rs += __shfl_xor(rs, 32);
    l_ = l_ * al + rs;

    // redistribute alpha to the o accumulator layout (q = quad*4 + r lives in lane quad*4+r)
    float alr[4];
#pragma unroll
    for (int r = 0; r < 4; ++r)
      alr[r] = __int_as_float(__builtin_amdgcn_ds_bpermute((quad * 4 + r) * 4,
                                                           __float_as_int(al)));
#pragma unroll
    for (int d = 0; d < 6; ++d)
#pragma unroll
      for (int r = 0; r < 4; ++r) o[d][r] *= alr[r];

    // pack P pairs to bf16x2: pk[sub][t] = (bf16(s[sub][2t]), bf16(s[sub][2t+1]))
    unsigned pk[4][2];
#pragma unroll
    for (int sub = 0; sub < 4; ++sub) {
      asm("v_cvt_pk_bf16_f32 %0, %1, %2" : "=v"(pk[sub][0]) : "v"(s[sub][0]), "v"(s[sub][1]));
      asm("v_cvt_pk_bf16_f32 %0, %1, %2" : "=v"(pk[sub][1]) : "v"(s[sub][2]), "v"(s[sub][3]));
    }

    // PV: A-fragment assembled in-register via ds_bpermute; B-fragment from staged V
#pragma unroll
    for (int c = 0; c < 2; ++c) {
      if (c < nchunk) {
        const int a00 = __builtin_amdgcn_ds_bpermute(addrA, (int)pk[c * 2][0]);
        const int a01 = __builtin_amdgcn_ds_bpermute(addrA, (int)pk[c * 2][1]);
        const int a10 = __builtin_amdgcn_ds_bpermute(addrA, (int)pk[c * 2 + 1][0]);
        const int a11 = __builtin_amdgcn_ds_bpermute(addrA, (int)pk[c * 2 + 1][1]);
        const int b00 = __builtin_amdgcn_ds_bpermute(addrB, (int)pk[c * 2][0]);
        const int b01 = __builtin_amdgcn_ds_bpermute(addrB, (int)pk[c * 2][1]);
        const int b10 = __builtin_amdgcn_ds_bpermute(addrB, (int)pk[c * 2 + 1][0]);
        const int b11 = __builtin_amdgcn_ds_bpermute(addrB, (int)pk[c * 2 + 1][1]);
        union { s16x8 v; int u[4]; } ap;
        ap.u[0] = hb ? a10 : a00;
        ap.u[1] = hb ? a11 : a01;
        ap.u[2] = hb ? b10 : b00;
        ap.u[3] = hb ? b11 : b01;
#pragma unroll
        for (int dblk = 0; dblk < 6; ++dblk) {
          const int d = dblk * 16 + l15;
          const s16x8 bv = *(const s16x8*)(&Vl[cur][d * 64 + (((c * 4 + quad) ^ (d & 7)) * 8)]);
          o[dblk] = __builtin_amdgcn_mfma_f32_16x16x32_bf16(ap.v, bv, o[dblk], 0, 0, 0);
        }
      }
    }

    __syncthreads();   // implicit vmcnt(0)+lgkmcnt(0) drain: next tile landed, cur free
    cur ^= 1;
  }

  // write ctx[b, q, h*96 + d] bf16 (o layout: row q = quad*4+r, col d = dblk*16+l15)
  const int b = bh >> 5, h = bh & 31;
  float invl[4];
#pragma unroll
  for (int r = 0; r < 4; ++r) {
    const int v = __builtin_amdgcn_ds_bpermute((quad * 4 + r) * 4, __float_as_int(l_));
    invl[r] = 1.0f / __int_as_float(v);
  }
#pragma unroll
  for (int d = 0; d < 6; ++d)
#pragma unroll
    for (int r = 0; r < 4; ++r) {
      const int row = q0 + quad * 4 + r;
      ctx[((size_t)(b * 2048 + row)) * 3072 + h * 96 + d * 16 + l15] = f2bf(o[d][r] * invl[r]);
    }
}

// ---------------- launch ----------------
extern "C" void kernel_launch(void* const* d_in, const int* in_sizes, int n_in,
                              void* d_out, int out_size, void* d_ws, size_t ws_size,
                              hipStream_t stream) {
  const float* x    = (const float*)d_in[0];   // [2,2048,3072]
  const float* Wqkv = (const float*)d_in[1];   // [9216,3072]
  const float* Wo   = (const float*)d_in[2];   // [3072,3072]
  float* out = (float*)d_out;                  // [2,2048,3072] fp32

  char* ws = (char*)d_ws;
  u16* wq_b  = (u16*)(ws);                  // 56,623,104 B
  u16* wo_b  = (u16*)(ws + 56623104);       // 18,874,368 B
  u16* x_b   = (u16*)(ws + 75497472);       // 25,165,824 B
  u16* qkv_b = (u16*)(ws + 100663296);      // 75,497,472 B
  u16* K_b   = (u16*)(ws + 176160768);      // 25,165,824 B
  u16* Vt_b  = (u16*)(ws + 201326592);      // 25,165,824 B
  u16* Q_b   = x_b;                         // alias: x dead after GEMM1
  u16* ctx_b = qkv_b;                       // alias: qkv dead after rope_split

  cvt_f32_bf16<<<27648, 256, 0, stream>>>(Wqkv, wq_b, 28311552 / 4);
  cvt_f32_bf16<<<9216,  256, 0, stream>>>(Wo,   wo_b,  9437184 / 4);
  cvt_f32_bf16<<<12288, 256, 0, stream>>>(x,    x_b,  12582912 / 4);

  // qkv = x @ Wqkv^T   [4096 x 9216], K=3072  (16 x 48 = 768 tiles = 3.00 rounds)
  gemm_nt256<3, true><<<768, 512, 0, stream>>>(x_b, wq_b, (void*)qkv_b, 4096, 9216, 3072);

  rope_split<<<4096, 256, 0, stream>>>(qkv_b, Q_b, K_b, Vt_b);

  attn<<<dim3(32, 64), 256, 0, stream>>>(Q_b, K_b, Vt_b, ctx_b);

  // out = ctx @ Wo^T   [4096 x 3072], K=3072, fp32 out  (16 x 16 = 256 tiles = 1.00 round)
  gemm_nt256<3, false><<<256, 512, 0, stream>>>(ctx_b, wo_b, (void*)out, 4096, 3072, 3072);
}